// Round 1
// baseline (1458.221 us; speedup 1.0000x reference)
//
#include <hip/hip_runtime.h>
#include <math.h>

// Problem constants (fixed-shape problem)
#define NPTS 8192
#define CCH  128
#define KNN  16
#define CS   16          // C / share_planes
#define BN_RS 0.9999950000374997f   // 1/sqrt(1 + 1e-5)

// ---------------------------------------------------------------------------
// Kernel A: KNN — for each query, the set of 16 nearest points by (d2, idx).
// Order within the 16 is irrelevant downstream (softmax/sum over k are
// permutation-invariant), so we only need the correct SET.
// G=16 threads per query scan interleaved candidate subsets from LDS tiles,
// keep per-thread top-16 lists in LDS (stride-17 padded), then merge via a
// 16-lane shuffle tournament.
// ---------------------------------------------------------------------------
#define AINF 3.0e38f

__global__ __launch_bounds__(128) void knn_kernel(const float* __restrict__ p,
                                                  int* __restrict__ oidx,
                                                  float* __restrict__ od2) {
    constexpr int TPB = 128, G = 16, QPB = TPB / G, TILE = 2048;
    __shared__ float4 s_pt[TILE];          // 32 KB
    __shared__ float  s_ld2[TPB * 17];     // 8.5 KB
    __shared__ int    s_lid[TPB * 17];     // 8.5 KB

    const int t    = threadIdx.x;
    const int sub  = t & (G - 1);
    const int qloc = t >> 4;
    const int q    = blockIdx.x * QPB + qloc;

    const float qx = p[q * 3 + 0], qy = p[q * 3 + 1], qz = p[q * 3 + 2];
    const float qsq = qx * qx + qy * qy + qz * qz;

    float* myd2 = &s_ld2[t * 17];
    int*   myid = &s_lid[t * 17];

    int   cnt  = 0;
    float kmax = AINF;   // current 16th-smallest d2 in my list (INF while filling)
    int   kid  = 0x7fffffff;
    int   amax = 0;      // slot of current max

    auto insert = [&](float dv, int jv) {
        if (cnt < KNN) {
            myd2[cnt] = dv; myid[cnt] = jv; ++cnt;
            if (cnt == KNN) {
                kmax = -AINF; kid = -1;
                #pragma unroll
                for (int e = 0; e < KNN; ++e) {
                    float v = myd2[e]; int id = myid[e];
                    if (v > kmax || (v == kmax && id > kid)) { kmax = v; kid = id; amax = e; }
                }
            }
        } else {
            myd2[amax] = dv; myid[amax] = jv;
            kmax = -AINF; kid = -1;
            #pragma unroll
            for (int e = 0; e < KNN; ++e) {
                float v = myd2[e]; int id = myid[e];
                if (v > kmax || (v == kmax && id > kid)) { kmax = v; kid = id; amax = e; }
            }
        }
    };

    for (int tb = 0; tb < NPTS; tb += TILE) {
        __syncthreads();
        for (int jj = t; jj < TILE; jj += TPB) {
            const int j = tb + jj;
            const float x = p[j * 3 + 0], y = p[j * 3 + 1], z = p[j * 3 + 2];
            s_pt[jj] = make_float4(x, y, z, x * x + y * y + z * z);
        }
        __syncthreads();
        for (int l = 0; l < TILE; l += 4 * G) {
            // 4 independent candidate loads for ILP
            const float4 c0 = s_pt[l + 0 * G + sub];
            const float4 c1 = s_pt[l + 1 * G + sub];
            const float4 c2 = s_pt[l + 2 * G + sub];
            const float4 c3 = s_pt[l + 3 * G + sub];
            const float d0 = qsq + c0.w - 2.f * (qx * c0.x + qy * c0.y + qz * c0.z);
            const float d1 = qsq + c1.w - 2.f * (qx * c1.x + qy * c1.y + qz * c1.z);
            const float d2 = qsq + c2.w - 2.f * (qx * c2.x + qy * c2.y + qz * c2.z);
            const float d3 = qsq + c3.w - 2.f * (qx * c3.x + qy * c3.y + qz * c3.z);
            const int j0 = tb + l + 0 * G + sub;
            const int j1 = tb + l + 1 * G + sub;
            const int j2 = tb + l + 2 * G + sub;
            const int j3 = tb + l + 3 * G + sub;
            if (d0 < kmax || (d0 == kmax && j0 < kid)) insert(d0, j0);
            if (d1 < kmax || (d1 == kmax && j1 < kid)) insert(d1, j1);
            if (d2 < kmax || (d2 == kmax && j2 < kid)) insert(d2, j2);
            if (d3 < kmax || (d3 == kmax && j3 < kid)) insert(d3, j3);
        }
    }

    // ---- merge 16 per-thread lists (all within one wave's 16-lane group) ----
    for (int r = 0; r < KNN; ++r) {
        // local minimum under (d2, idx)
        float lbd = AINF; int lbi = 0x7fffffff; int ls = -1;
        #pragma unroll
        for (int e = 0; e < KNN; ++e) {
            float v = myd2[e]; int id = myid[e];
            if (v < lbd || (v == lbd && id < lbi)) { lbd = v; lbi = id; ls = e; }
        }
        // group-of-16 lexicographic min via shuffles
        float gbd = lbd; int gbi = lbi;
        #pragma unroll
        for (int mk = 1; mk < 16; mk <<= 1) {
            float od = __shfl_xor(gbd, mk);
            int   oi = __shfl_xor(gbi, mk);
            if (od < gbd || (od == gbd && oi < gbi)) { gbd = od; gbi = oi; }
        }
        // owner removes the winner from its list
        if (lbd == gbd && lbi == gbi) myd2[ls] = AINF;
        if (sub == 0) {
            oidx[q * KNN + r] = gbi;
            od2 [q * KNN + r] = gbd;
        }
    }
}

// ---------------------------------------------------------------------------
// Kernel B: three fp32 GEMMs  xq/xk/xv = x @ W + b     (8192 x 128 x 128)
// 64x64 output tile per block, 4x4 register blocking, K sliced by 64.
// ---------------------------------------------------------------------------
__global__ __launch_bounds__(256) void gemm3_kernel(
    const float* __restrict__ x,
    const float* __restrict__ Wq, const float* __restrict__ bq,
    const float* __restrict__ Wk, const float* __restrict__ bk,
    const float* __restrict__ Wv, const float* __restrict__ bv,
    float* __restrict__ xq, float* __restrict__ xk, float* __restrict__ xv) {
    const int which = blockIdx.z;
    const float* W    = (which == 0) ? Wq : (which == 1) ? Wk : Wv;
    const float* bias = (which == 0) ? bq : (which == 1) ? bk : bv;
    float*       out  = (which == 0) ? xq : (which == 1) ? xk : xv;

    const int row0 = blockIdx.x * 64;
    const int col0 = blockIdx.y * 64;

    __shared__ float As[64][68];
    __shared__ float Bs[64][68];

    const int t  = threadIdx.x;
    const int lr = t >> 4;          // 0..15 (loader row group)
    const int lc = t & 15;          // 0..15 (loader col group)
    const int or0 = (t >> 4) * 4;   // output rows   (0..60)
    const int oc0 = (t & 15) * 4;   // output cols   (0..60)

    float acc[4][4] = {};

    for (int kk = 0; kk < CCH; kk += 64) {
        __syncthreads();
        #pragma unroll
        for (int i = 0; i < 4; ++i) {
            const int r = lr + i * 16;
            *(float4*)&As[r][lc * 4] =
                *(const float4*)&x[(size_t)(row0 + r) * CCH + kk + lc * 4];
            *(float4*)&Bs[r][lc * 4] =
                *(const float4*)&W[(size_t)(kk + r) * CCH + col0 + lc * 4];
        }
        __syncthreads();
        #pragma unroll 8
        for (int k = 0; k < 64; ++k) {
            const float a0 = As[or0 + 0][k];
            const float a1 = As[or0 + 1][k];
            const float a2 = As[or0 + 2][k];
            const float a3 = As[or0 + 3][k];
            const float4 b = *(const float4*)&Bs[k][oc0];
            acc[0][0] += a0 * b.x; acc[0][1] += a0 * b.y; acc[0][2] += a0 * b.z; acc[0][3] += a0 * b.w;
            acc[1][0] += a1 * b.x; acc[1][1] += a1 * b.y; acc[1][2] += a1 * b.z; acc[1][3] += a1 * b.w;
            acc[2][0] += a2 * b.x; acc[2][1] += a2 * b.y; acc[2][2] += a2 * b.z; acc[2][3] += a2 * b.w;
            acc[3][0] += a3 * b.x; acc[3][1] += a3 * b.y; acc[3][2] += a3 * b.z; acc[3][3] += a3 * b.w;
        }
    }

    const float4 bb = *(const float4*)&bias[col0 + oc0];
    #pragma unroll
    for (int i = 0; i < 4; ++i) {
        const int r = row0 + or0 + i;
        float4 o;
        o.x = acc[i][0] + bb.x;
        o.y = acc[i][1] + bb.y;
        o.z = acc[i][2] + bb.z;
        o.w = acc[i][3] + bb.w;
        *(float4*)&out[(size_t)r * CCH + col0 + oc0] = o;
    }
}

// ---------------------------------------------------------------------------
// Kernel C: fused per-point attention.  1 block (256 thr) = 1 query point.
// Phase 1: (k = t>>4, c-chunk = (t&15)*8): gather xk/xv rows, compute
//          pr = linear_p(p_r), wv = relu(bn(xq - xk + pr)), val = xv*dw + pr
// Phase 2: (k, m): w1[k][m] = wv[k][:] . Ww1T[m][:]  (b128 LDS reads)
//          -> bn relu -> w2 = r @ Ww2
// Phase 3: softmax over k per column m
// Phase 4: out[c] = sum_k val[k][c] * wn[k][c&15]
// ---------------------------------------------------------------------------
#define LD8(dst, arr) do { \
    const float4 _a = *(const float4*)&(arr)[c0];     \
    const float4 _b = *(const float4*)&(arr)[c0 + 4]; \
    dst[0] = _a.x; dst[1] = _a.y; dst[2] = _a.z; dst[3] = _a.w; \
    dst[4] = _b.x; dst[5] = _b.y; dst[6] = _b.z; dst[7] = _b.w; } while (0)

__global__ __launch_bounds__(256) void fused_kernel(
    const float* __restrict__ p,
    const float* __restrict__ xqg, const float* __restrict__ xkg, const float* __restrict__ xvg,
    const int* __restrict__ nidx, const float* __restrict__ nd2,
    const float* __restrict__ Wp1, const float* __restrict__ bp1,
    const float* __restrict__ g1,  const float* __restrict__ be1,
    const float* __restrict__ Wp2, const float* __restrict__ bp2,
    const float* __restrict__ g2,  const float* __restrict__ be2,
    const float* __restrict__ Ww1, const float* __restrict__ bw1,
    const float* __restrict__ g3,  const float* __restrict__ be3,
    const float* __restrict__ Ww2, const float* __restrict__ bw2,
    float* __restrict__ out) {
    const int i = blockIdx.x;
    const int t = threadIdx.x;

    __shared__ float s_wv[16][132];
    __shared__ float s_val[16][132];
    __shared__ float s_w1t[16][132];   // Ww1 transposed: [m][c]
    __shared__ float s_wp2[3][128];
    __shared__ float s_bp2[128], s_g2s[128], s_be2[128], s_xq[128];
    __shared__ float s_r[16][17], s_w2[16][17], s_e[16][17], s_wn[16][17];
    __shared__ float s_ww2[256];       // [mm][m] row-major
    __shared__ float s_sm[64];         // bw1 | g3*rs | be3 | bw2

    // ---- stage weights / per-point query row ----
    if (t < 128) {
        const int c = t;
        s_wp2[0][c] = Wp2[c];
        s_wp2[1][c] = Wp2[128 + c];
        s_wp2[2][c] = Wp2[256 + c];
        s_bp2[c]    = bp2[c];
        s_g2s[c]    = g2[c] * BN_RS;
        s_be2[c]    = be2[c];
        s_xq[c]     = xqg[(size_t)i * CCH + c];
    } else {
        const int u = t - 128;
        if (u < 16)      s_sm[u] = bw1[u];
        else if (u < 32) s_sm[u] = g3[u - 16] * BN_RS;
        else if (u < 48) s_sm[u] = be3[u - 32];
        else if (u < 64) s_sm[u] = bw2[u - 48];
    }
    s_ww2[t] = Ww2[t];
    #pragma unroll
    for (int e = t; e < 2048; e += 256) s_w1t[e & 15][e >> 4] = Ww1[e];
    __syncthreads();

    // ---- phase 1 ----
    const int k  = t >> 4;      // 0..15 neighbor
    const int tl = t & 15;
    const int c0 = tl * 8;

    const int   jn  = nidx[i * KNN + k];
    const float d2v = nd2[i * KNN + k];
    const float dw  = expf(-sqrtf(fmaxf(d2v, 0.f)));

    const float prx = p[jn * 3 + 0] - p[i * 3 + 0];
    const float pry = p[jn * 3 + 1] - p[i * 3 + 1];
    const float prz = p[jn * 3 + 2] - p[i * 3 + 2];
    float tt[3];
    #pragma unroll
    for (int e = 0; e < 3; ++e) {
        float v = prx * Wp1[0 * 3 + e] + pry * Wp1[1 * 3 + e] + prz * Wp1[2 * 3 + e] + bp1[e];
        v = v * (g1[e] * BN_RS) + be1[e];
        tt[e] = fmaxf(v, 0.f);
    }

    {
        const float4 a0 = *(const float4*)&xkg[(size_t)jn * CCH + c0];
        const float4 a1 = *(const float4*)&xkg[(size_t)jn * CCH + c0 + 4];
        const float4 b0 = *(const float4*)&xvg[(size_t)jn * CCH + c0];
        const float4 b1 = *(const float4*)&xvg[(size_t)jn * CCH + c0 + 4];
        const float xk8[8] = {a0.x, a0.y, a0.z, a0.w, a1.x, a1.y, a1.z, a1.w};
        const float xv8[8] = {b0.x, b0.y, b0.z, b0.w, b1.x, b1.y, b1.z, b1.w};
        float w08[8], w18[8], w28[8], bp8[8], xq8[8], gs8[8], bb8[8];
        LD8(w08, s_wp2[0]); LD8(w18, s_wp2[1]); LD8(w28, s_wp2[2]);
        LD8(bp8, s_bp2); LD8(xq8, s_xq); LD8(gs8, s_g2s); LD8(bb8, s_be2);
        float wv8[8], val8[8];
        #pragma unroll
        for (int d = 0; d < 8; ++d) {
            const float pr = tt[0] * w08[d] + tt[1] * w18[d] + tt[2] * w28[d] + bp8[d];
            float wvv = (xq8[d] - xk8[d]) + pr;
            wvv = fmaxf(wvv * gs8[d] + bb8[d], 0.f);
            wv8[d]  = wvv;
            val8[d] = xv8[d] * dw + pr;
        }
        *(float4*)&s_wv [k][c0]     = make_float4(wv8[0], wv8[1], wv8[2], wv8[3]);
        *(float4*)&s_wv [k][c0 + 4] = make_float4(wv8[4], wv8[5], wv8[6], wv8[7]);
        *(float4*)&s_val[k][c0]     = make_float4(val8[0], val8[1], val8[2], val8[3]);
        *(float4*)&s_val[k][c0 + 4] = make_float4(val8[4], val8[5], val8[6], val8[7]);
    }
    __syncthreads();

    // ---- phase 2: w1 = wv @ Ww1 + bw1 -> bn relu -> w2 = r @ Ww2 + bw2 ----
    const int k2 = t >> 4, m = t & 15;
    float acc = s_sm[m];   // bw1[m]
    #pragma unroll
    for (int c = 0; c < CCH; c += 4) {
        const float4 a = *(const float4*)&s_wv[k2][c];
        const float4 b = *(const float4*)&s_w1t[m][c];
        acc += a.x * b.x; acc += a.y * b.y; acc += a.z * b.z; acc += a.w * b.w;
    }
    const float rr = fmaxf(acc * s_sm[16 + m] + s_sm[32 + m], 0.f);
    s_r[k2][m] = rr;
    __syncthreads();

    float acc2 = s_sm[48 + m];   // bw2[m]
    #pragma unroll
    for (int mm = 0; mm < 16; ++mm) acc2 += s_r[k2][mm] * s_ww2[mm * 16 + m];
    s_w2[k2][m] = acc2;
    __syncthreads();

    // ---- phase 3: softmax over k (column m) ----
    float mx = s_w2[0][m];
    #pragma unroll
    for (int kk = 1; kk < 16; ++kk) mx = fmaxf(mx, s_w2[kk][m]);
    const float ev = expf(acc2 - mx);
    s_e[k2][m] = ev;
    __syncthreads();
    float ssum = 0.f;
    #pragma unroll
    for (int kk = 0; kk < 16; ++kk) ssum += s_e[kk][m];
    s_wn[k2][m] = ev / ssum;
    __syncthreads();

    // ---- phase 4: out[c] = sum_k val[k][c] * wn[k][c & 15] ----
    if (t < 128) {
        const int c = t, mc = t & 15;
        float o = 0.f;
        #pragma unroll
        for (int kk = 0; kk < 16; ++kk) o += s_val[kk][c] * s_wn[kk][mc];
        out[(size_t)i * CCH + c] = o;
    }
}

// ---------------------------------------------------------------------------
extern "C" void kernel_launch(void* const* d_in, const int* in_sizes, int n_in,
                              void* d_out, int out_size, void* d_ws, size_t ws_size,
                              hipStream_t stream) {
    (void)in_sizes; (void)n_in; (void)out_size; (void)ws_size;
    const float* p   = (const float*)d_in[0];
    const float* x   = (const float*)d_in[1];
    const float* Wq  = (const float*)d_in[2];
    const float* bq  = (const float*)d_in[3];
    const float* Wk  = (const float*)d_in[4];
    const float* bk  = (const float*)d_in[5];
    const float* Wv  = (const float*)d_in[6];
    const float* bv  = (const float*)d_in[7];
    const float* Wp1 = (const float*)d_in[8];
    const float* bp1 = (const float*)d_in[9];
    const float* g1  = (const float*)d_in[10];
    const float* be1 = (const float*)d_in[11];
    const float* Wp2 = (const float*)d_in[12];
    const float* bp2 = (const float*)d_in[13];
    const float* g2  = (const float*)d_in[14];
    const float* be2 = (const float*)d_in[15];
    const float* Ww1 = (const float*)d_in[16];
    const float* bw1 = (const float*)d_in[17];
    const float* g3  = (const float*)d_in[18];
    const float* be3 = (const float*)d_in[19];
    const float* Ww2 = (const float*)d_in[20];
    const float* bw2 = (const float*)d_in[21];
    float* out = (float*)d_out;

    // workspace layout (13.5 MB total)
    char* ws = (char*)d_ws;
    int*   idxb = (int*)ws;                                   // 512 KB
    float* d2b  = (float*)(ws + (size_t)512 * 1024);          // 512 KB
    float* xqb  = (float*)(ws + (size_t)1 * 1024 * 1024);     // 4 MB
    float* xkb  = (float*)(ws + (size_t)5 * 1024 * 1024);     // 4 MB
    float* xvb  = (float*)(ws + (size_t)9 * 1024 * 1024);     // 4 MB

    knn_kernel<<<dim3(NPTS / 8), dim3(128), 0, stream>>>(p, idxb, d2b);
    gemm3_kernel<<<dim3(NPTS / 64, CCH / 64, 3), dim3(256), 0, stream>>>(
        x, Wq, bq, Wk, bk, Wv, bv, xqb, xkb, xvb);
    fused_kernel<<<dim3(NPTS), dim3(256), 0, stream>>>(
        p, xqb, xkb, xvb, idxb, d2b,
        Wp1, bp1, g1, be1, Wp2, bp2, g2, be2, Ww1, bw1, g3, be3, Ww2, bw2, out);
}

// Round 2
// 175.475 us; speedup vs baseline: 8.3101x; 8.3101x over previous
//
#include <hip/hip_runtime.h>
#include <math.h>

// Problem constants (fixed-shape problem)
#define NPTS 8192
#define CCH  128
#define KNN  16
#define BN_RS 0.9999950000374997f   // 1/sqrt(1 + 1e-5)

typedef unsigned long long u64;

// ---------------------------------------------------------------------------
// Kernel P: pack candidate points as float4 (x, y, z, |p|^2)
// ---------------------------------------------------------------------------
__global__ __launch_bounds__(256) void pack_kernel(const float* __restrict__ p,
                                                   float4* __restrict__ c4) {
    const int j = blockIdx.x * 256 + threadIdx.x;
    if (j < NPTS) {
        const float x = p[3 * j + 0], y = p[3 * j + 1], z = p[3 * j + 2];
        c4[j] = make_float4(x, y, z, x * x + y * y + z * z);
    }
}

// ---------------------------------------------------------------------------
// Kernel A: KNN via 2-pass threshold select.
//   Keys are u64 = (f32 bits of clamped d2) << 32 | idx  -> exact lexicographic
//   (d2, idx) order, matching jax top_k tie-breaks.
//   Pass 1: per-lane min over its 1/64 candidate subset (8 queries per wave).
//   tau_q = 16th-smallest of the 64 lane minima (bitonic sort across lanes)
//           -> provable upper bound on the true 16th-smallest key.
//   Pass 2: recompute d2 (bitwise-identical code) and collect keys <= tau_q
//           (expected ~18-25 per query) into per-query LDS lists.
//   Final: bitonic-sort collected keys, emit smallest 16.
// ---------------------------------------------------------------------------
#define QW   8          // queries per wave
#define CAP  96         // collect capacity per query
#define TILE 2048       // candidates staged per LDS tile

__device__ __forceinline__ u64 bitonic64(u64 v, const int lane) {
    #pragma unroll
    for (int k = 2; k <= 64; k <<= 1) {
        #pragma unroll
        for (int j = k >> 1; j > 0; j >>= 1) {
            const u64  o       = __shfl_xor(v, j);
            const bool up      = ((lane & k) == 0);
            const bool lower   = ((lane & j) == 0);
            const bool takemin = (lower == up);
            const bool sw      = ((o < v) == takemin);
            v = sw ? o : v;
        }
    }
    return v;   // ascending by lane
}

__device__ __forceinline__ u64 make_key(const float4 c, const float m2x, const float m2y,
                                        const float m2z, const float qb, const u64 jlo) {
    float d2 = fmaf(m2x, c.x, fmaf(m2y, c.y, fmaf(m2z, c.z, c.w + qb)));
    d2 = fmaxf(d2, 0.0f);
    return ((u64)__float_as_uint(d2) << 32) | jlo;
}

__global__ __launch_bounds__(256) void knn_kernel(const float4* __restrict__ c4,
                                                  int* __restrict__ oidx,
                                                  float* __restrict__ od2) {
    __shared__ float4 s_pt[TILE];            // 32 KB
    __shared__ u64    s_col[4][QW][CAP];     // 24 KB
    __shared__ int    s_cnt[4][QW];

    const int t     = threadIdx.x;
    const int wave  = t >> 6;
    const int lane  = t & 63;
    const int qbase = (blockIdx.x * 4 + wave) * QW;

    // query constants (wave-uniform)
    float m2x[QW], m2y[QW], m2z[QW], qb[QW];
    #pragma unroll
    for (int qi = 0; qi < QW; ++qi) {
        const float4 q = c4[qbase + qi];
        m2x[qi] = -2.0f * q.x;
        m2y[qi] = -2.0f * q.y;
        m2z[qi] = -2.0f * q.z;
        qb[qi]  = q.w;
    }

    if (lane < QW) s_cnt[wave][lane] = 0;    // synced by first staging barrier

    // ---- pass 1: per-lane minima ----
    u64 best[QW];
    #pragma unroll
    for (int qi = 0; qi < QW; ++qi) best[qi] = ~0ull;

    for (int tb = 0; tb < NPTS; tb += TILE) {
        __syncthreads();
        for (int jj = t; jj < TILE; jj += 256) s_pt[jj] = c4[tb + jj];
        __syncthreads();
        for (int l = lane; l < TILE; l += 64) {
            const float4 c   = s_pt[l];
            const u64    jlo = (u64)(unsigned)(tb + l);
            #pragma unroll
            for (int qi = 0; qi < QW; ++qi) {
                const u64 key = make_key(c, m2x[qi], m2y[qi], m2z[qi], qb[qi], jlo);
                best[qi] = (key < best[qi]) ? key : best[qi];
            }
        }
    }

    // ---- tau_q = 16th smallest lane-min ----
    u64 tau[QW];
    #pragma unroll
    for (int qi = 0; qi < QW; ++qi) {
        const u64 sorted = bitonic64(best[qi], lane);
        tau[qi] = __shfl(sorted, 15);
    }

    // ---- pass 2: collect keys <= tau ----
    for (int tb = 0; tb < NPTS; tb += TILE) {
        __syncthreads();
        for (int jj = t; jj < TILE; jj += 256) s_pt[jj] = c4[tb + jj];
        __syncthreads();
        for (int l = lane; l < TILE; l += 64) {
            const float4 c   = s_pt[l];
            const u64    jlo = (u64)(unsigned)(tb + l);
            #pragma unroll
            for (int qi = 0; qi < QW; ++qi) {
                const u64 key = make_key(c, m2x[qi], m2y[qi], m2z[qi], qb[qi], jlo);
                if (key <= tau[qi]) {
                    const int pos = atomicAdd(&s_cnt[wave][qi], 1);
                    if (pos < CAP) s_col[wave][qi][pos] = key;
                }
            }
        }
    }
    __syncthreads();

    // ---- final select per query ----
    #pragma unroll 1
    for (int qi = 0; qi < QW; ++qi) {
        const int q = qbase + qi;
        const int M = s_cnt[wave][qi];
        if (M <= 64) {
            u64 v = (lane < M) ? s_col[wave][qi][lane] : ~0ull;
            v = bitonic64(v, lane);
            if (lane < KNN) {
                oidx[q * KNN + lane] = (int)(v & 0xffffffffu);
                od2 [q * KNN + lane] = __uint_as_float((unsigned)(v >> 32));
            }
        } else {
            // extremely rare fallback: iterative extraction over up to CAP entries
            const int Mc = (M < CAP) ? M : CAP;
            u64 e0 = (lane      < Mc) ? s_col[wave][qi][lane]      : ~0ull;
            u64 e1 = (lane + 64 < Mc) ? s_col[wave][qi][lane + 64] : ~0ull;
            for (int r = 0; r < KNN; ++r) {
                const u64 loc = (e0 < e1) ? e0 : e1;
                u64 g = loc;
                #pragma unroll
                for (int mk = 32; mk >= 1; mk >>= 1) {
                    const u64 o = __shfl_xor(g, mk);
                    g = (o < g) ? o : g;
                }
                if (loc == g) { if (e0 == g) e0 = ~0ull; else e1 = ~0ull; }
                if (lane == 0) {
                    oidx[q * KNN + r] = (int)(g & 0xffffffffu);
                    od2 [q * KNN + r] = __uint_as_float((unsigned)(g >> 32));
                }
            }
        }
    }
}

// ---------------------------------------------------------------------------
// Kernel B: three fp32 GEMMs  xq/xk/xv = x @ W + b     (8192 x 128 x 128)
// ---------------------------------------------------------------------------
__global__ __launch_bounds__(256) void gemm3_kernel(
    const float* __restrict__ x,
    const float* __restrict__ Wq, const float* __restrict__ bq,
    const float* __restrict__ Wk, const float* __restrict__ bk,
    const float* __restrict__ Wv, const float* __restrict__ bv,
    float* __restrict__ xq, float* __restrict__ xk, float* __restrict__ xv) {
    const int which = blockIdx.z;
    const float* W    = (which == 0) ? Wq : (which == 1) ? Wk : Wv;
    const float* bias = (which == 0) ? bq : (which == 1) ? bk : bv;
    float*       out  = (which == 0) ? xq : (which == 1) ? xk : xv;

    const int row0 = blockIdx.x * 64;
    const int col0 = blockIdx.y * 64;

    __shared__ float As[64][68];
    __shared__ float Bs[64][68];

    const int t  = threadIdx.x;
    const int lr = t >> 4;
    const int lc = t & 15;
    const int or0 = (t >> 4) * 4;
    const int oc0 = (t & 15) * 4;

    float acc[4][4] = {};

    for (int kk = 0; kk < CCH; kk += 64) {
        __syncthreads();
        #pragma unroll
        for (int i = 0; i < 4; ++i) {
            const int r = lr + i * 16;
            *(float4*)&As[r][lc * 4] =
                *(const float4*)&x[(size_t)(row0 + r) * CCH + kk + lc * 4];
            *(float4*)&Bs[r][lc * 4] =
                *(const float4*)&W[(size_t)(kk + r) * CCH + col0 + lc * 4];
        }
        __syncthreads();
        #pragma unroll 8
        for (int k = 0; k < 64; ++k) {
            const float a0 = As[or0 + 0][k];
            const float a1 = As[or0 + 1][k];
            const float a2 = As[or0 + 2][k];
            const float a3 = As[or0 + 3][k];
            const float4 b = *(const float4*)&Bs[k][oc0];
            acc[0][0] += a0 * b.x; acc[0][1] += a0 * b.y; acc[0][2] += a0 * b.z; acc[0][3] += a0 * b.w;
            acc[1][0] += a1 * b.x; acc[1][1] += a1 * b.y; acc[1][2] += a1 * b.z; acc[1][3] += a1 * b.w;
            acc[2][0] += a2 * b.x; acc[2][1] += a2 * b.y; acc[2][2] += a2 * b.z; acc[2][3] += a2 * b.w;
            acc[3][0] += a3 * b.x; acc[3][1] += a3 * b.y; acc[3][2] += a3 * b.z; acc[3][3] += a3 * b.w;
        }
    }

    const float4 bb = *(const float4*)&bias[col0 + oc0];
    #pragma unroll
    for (int i = 0; i < 4; ++i) {
        const int r = row0 + or0 + i;
        float4 o;
        o.x = acc[i][0] + bb.x;
        o.y = acc[i][1] + bb.y;
        o.z = acc[i][2] + bb.z;
        o.w = acc[i][3] + bb.w;
        *(float4*)&out[(size_t)r * CCH + col0 + oc0] = o;
    }
}

// ---------------------------------------------------------------------------
// Kernel C: fused per-point attention.  1 block (256 thr) = 1 query point.
// ---------------------------------------------------------------------------
#define LD8(dst, arr) do { \
    const float4 _a = *(const float4*)&(arr)[c0];     \
    const float4 _b = *(const float4*)&(arr)[c0 + 4]; \
    dst[0] = _a.x; dst[1] = _a.y; dst[2] = _a.z; dst[3] = _a.w; \
    dst[4] = _b.x; dst[5] = _b.y; dst[6] = _b.z; dst[7] = _b.w; } while (0)

__global__ __launch_bounds__(256) void fused_kernel(
    const float* __restrict__ p,
    const float* __restrict__ xqg, const float* __restrict__ xkg, const float* __restrict__ xvg,
    const int* __restrict__ nidx, const float* __restrict__ nd2,
    const float* __restrict__ Wp1, const float* __restrict__ bp1,
    const float* __restrict__ g1,  const float* __restrict__ be1,
    const float* __restrict__ Wp2, const float* __restrict__ bp2,
    const float* __restrict__ g2,  const float* __restrict__ be2,
    const float* __restrict__ Ww1, const float* __restrict__ bw1,
    const float* __restrict__ g3,  const float* __restrict__ be3,
    const float* __restrict__ Ww2, const float* __restrict__ bw2,
    float* __restrict__ out) {
    const int i = blockIdx.x;
    const int t = threadIdx.x;

    __shared__ float s_wv[16][132];
    __shared__ float s_val[16][132];
    __shared__ float s_w1t[16][132];   // Ww1 transposed: [m][c]
    __shared__ float s_wp2[3][128];
    __shared__ float s_bp2[128], s_g2s[128], s_be2[128], s_xq[128];
    __shared__ float s_r[16][17], s_w2[16][17], s_e[16][17], s_wn[16][17];
    __shared__ float s_ww2[256];       // [mm][m] row-major
    __shared__ float s_sm[64];         // bw1 | g3*rs | be3 | bw2

    if (t < 128) {
        const int c = t;
        s_wp2[0][c] = Wp2[c];
        s_wp2[1][c] = Wp2[128 + c];
        s_wp2[2][c] = Wp2[256 + c];
        s_bp2[c]    = bp2[c];
        s_g2s[c]    = g2[c] * BN_RS;
        s_be2[c]    = be2[c];
        s_xq[c]     = xqg[(size_t)i * CCH + c];
    } else {
        const int u = t - 128;
        if (u < 16)      s_sm[u] = bw1[u];
        else if (u < 32) s_sm[u] = g3[u - 16] * BN_RS;
        else if (u < 48) s_sm[u] = be3[u - 32];
        else if (u < 64) s_sm[u] = bw2[u - 48];
    }
    s_ww2[t] = Ww2[t];
    #pragma unroll
    for (int e = t; e < 2048; e += 256) s_w1t[e & 15][e >> 4] = Ww1[e];
    __syncthreads();

    // ---- phase 1 ----
    const int k  = t >> 4;
    const int tl = t & 15;
    const int c0 = tl * 8;

    const int   jn  = nidx[i * KNN + k];
    const float d2v = nd2[i * KNN + k];
    const float dw  = expf(-sqrtf(fmaxf(d2v, 0.f)));

    const float prx = p[jn * 3 + 0] - p[i * 3 + 0];
    const float pry = p[jn * 3 + 1] - p[i * 3 + 1];
    const float prz = p[jn * 3 + 2] - p[i * 3 + 2];
    float tt[3];
    #pragma unroll
    for (int e = 0; e < 3; ++e) {
        float v = prx * Wp1[0 * 3 + e] + pry * Wp1[1 * 3 + e] + prz * Wp1[2 * 3 + e] + bp1[e];
        v = v * (g1[e] * BN_RS) + be1[e];
        tt[e] = fmaxf(v, 0.f);
    }

    {
        const float4 a0 = *(const float4*)&xkg[(size_t)jn * CCH + c0];
        const float4 a1 = *(const float4*)&xkg[(size_t)jn * CCH + c0 + 4];
        const float4 b0 = *(const float4*)&xvg[(size_t)jn * CCH + c0];
        const float4 b1 = *(const float4*)&xvg[(size_t)jn * CCH + c0 + 4];
        const float xk8[8] = {a0.x, a0.y, a0.z, a0.w, a1.x, a1.y, a1.z, a1.w};
        const float xv8[8] = {b0.x, b0.y, b0.z, b0.w, b1.x, b1.y, b1.z, b1.w};
        float w08[8], w18[8], w28[8], bp8[8], xq8[8], gs8[8], bb8[8];
        LD8(w08, s_wp2[0]); LD8(w18, s_wp2[1]); LD8(w28, s_wp2[2]);
        LD8(bp8, s_bp2); LD8(xq8, s_xq); LD8(gs8, s_g2s); LD8(bb8, s_be2);
        float wv8[8], val8[8];
        #pragma unroll
        for (int d = 0; d < 8; ++d) {
            const float pr = tt[0] * w08[d] + tt[1] * w18[d] + tt[2] * w28[d] + bp8[d];
            float wvv = (xq8[d] - xk8[d]) + pr;
            wvv = fmaxf(wvv * gs8[d] + bb8[d], 0.f);
            wv8[d]  = wvv;
            val8[d] = xv8[d] * dw + pr;
        }
        *(float4*)&s_wv [k][c0]     = make_float4(wv8[0], wv8[1], wv8[2], wv8[3]);
        *(float4*)&s_wv [k][c0 + 4] = make_float4(wv8[4], wv8[5], wv8[6], wv8[7]);
        *(float4*)&s_val[k][c0]     = make_float4(val8[0], val8[1], val8[2], val8[3]);
        *(float4*)&s_val[k][c0 + 4] = make_float4(val8[4], val8[5], val8[6], val8[7]);
    }
    __syncthreads();

    // ---- phase 2 ----
    const int k2 = t >> 4, m = t & 15;
    float acc = s_sm[m];
    #pragma unroll
    for (int c = 0; c < CCH; c += 4) {
        const float4 a = *(const float4*)&s_wv[k2][c];
        const float4 b = *(const float4*)&s_w1t[m][c];
        acc += a.x * b.x; acc += a.y * b.y; acc += a.z * b.z; acc += a.w * b.w;
    }
    const float rr = fmaxf(acc * s_sm[16 + m] + s_sm[32 + m], 0.f);
    s_r[k2][m] = rr;
    __syncthreads();

    float acc2 = s_sm[48 + m];
    #pragma unroll
    for (int mm = 0; mm < 16; ++mm) acc2 += s_r[k2][mm] * s_ww2[mm * 16 + m];
    s_w2[k2][m] = acc2;
    __syncthreads();

    // ---- phase 3: softmax over k ----
    float mx = s_w2[0][m];
    #pragma unroll
    for (int kk = 1; kk < 16; ++kk) mx = fmaxf(mx, s_w2[kk][m]);
    const float ev = expf(acc2 - mx);
    s_e[k2][m] = ev;
    __syncthreads();
    float ssum = 0.f;
    #pragma unroll
    for (int kk = 0; kk < 16; ++kk) ssum += s_e[kk][m];
    s_wn[k2][m] = ev / ssum;
    __syncthreads();

    // ---- phase 4 ----
    if (t < 128) {
        const int c = t, mc = t & 15;
        float o = 0.f;
        #pragma unroll
        for (int kk = 0; kk < 16; ++kk) o += s_val[kk][c] * s_wn[kk][mc];
        out[(size_t)i * CCH + c] = o;
    }
}

// ---------------------------------------------------------------------------
extern "C" void kernel_launch(void* const* d_in, const int* in_sizes, int n_in,
                              void* d_out, int out_size, void* d_ws, size_t ws_size,
                              hipStream_t stream) {
    (void)in_sizes; (void)n_in; (void)out_size; (void)ws_size;
    const float* p   = (const float*)d_in[0];
    const float* x   = (const float*)d_in[1];
    const float* Wq  = (const float*)d_in[2];
    const float* bq  = (const float*)d_in[3];
    const float* Wk  = (const float*)d_in[4];
    const float* bk  = (const float*)d_in[5];
    const float* Wv  = (const float*)d_in[6];
    const float* bv  = (const float*)d_in[7];
    const float* Wp1 = (const float*)d_in[8];
    const float* bp1 = (const float*)d_in[9];
    const float* g1  = (const float*)d_in[10];
    const float* be1 = (const float*)d_in[11];
    const float* Wp2 = (const float*)d_in[12];
    const float* bp2 = (const float*)d_in[13];
    const float* g2  = (const float*)d_in[14];
    const float* be2 = (const float*)d_in[15];
    const float* Ww1 = (const float*)d_in[16];
    const float* bw1 = (const float*)d_in[17];
    const float* g3  = (const float*)d_in[18];
    const float* be3 = (const float*)d_in[19];
    const float* Ww2 = (const float*)d_in[20];
    const float* bw2 = (const float*)d_in[21];
    float* out = (float*)d_out;

    // workspace layout
    char* ws = (char*)d_ws;
    int*    idxb = (int*)ws;                                   // 512 KB
    float*  d2b  = (float*)(ws + (size_t)512 * 1024);          // 512 KB
    float*  xqb  = (float*)(ws + (size_t)1 * 1024 * 1024);     // 4 MB
    float*  xkb  = (float*)(ws + (size_t)5 * 1024 * 1024);     // 4 MB
    float*  xvb  = (float*)(ws + (size_t)9 * 1024 * 1024);     // 4 MB
    float4* c4b  = (float4*)(ws + (size_t)13 * 1024 * 1024);   // 128 KB

    pack_kernel<<<dim3(NPTS / 256), dim3(256), 0, stream>>>(p, c4b);
    knn_kernel<<<dim3(NPTS / 32), dim3(256), 0, stream>>>(c4b, idxb, d2b);
    gemm3_kernel<<<dim3(NPTS / 64, CCH / 64, 3), dim3(256), 0, stream>>>(
        x, Wq, bq, Wk, bk, Wv, bv, xqb, xkb, xvb);
    fused_kernel<<<dim3(NPTS), dim3(256), 0, stream>>>(
        p, xqb, xkb, xvb, idxb, d2b,
        Wp1, bp1, g1, be1, Wp2, bp2, g2, be2, Ww1, bw1, g3, be3, Ww2, bw2, out);
}

// Round 3
// 128.919 us; speedup vs baseline: 11.3112x; 1.3611x over previous
//
#include <hip/hip_runtime.h>
#include <math.h>

// Problem constants (fixed-shape problem)
#define NPTS 8192
#define CCH  128
#define KNN  16
#define BN_RS 0.9999950000374997f   // 1/sqrt(1 + 1e-5)

typedef unsigned long long u64;

// ---------------------------------------------------------------------------
// Kernel P: pack candidate points as float4 (x, y, z, |p|^2)
// ---------------------------------------------------------------------------
__global__ __launch_bounds__(256) void pack_kernel(const float* __restrict__ p,
                                                   float4* __restrict__ c4) {
    const int j = blockIdx.x * 256 + threadIdx.x;
    if (j < NPTS) {
        const float x = p[3 * j + 0], y = p[3 * j + 1], z = p[3 * j + 2];
        c4[j] = make_float4(x, y, z, x * x + y * y + z * z);
    }
}

// ---------------------------------------------------------------------------
// Kernel A: KNN via 2-pass threshold select.
//   Pass 1: per-lane float min (+idx) over its 1/64 candidate subset.
//           Strict '<' keeps the smallest idx on d2 ties (candidates arrive in
//           increasing idx per lane) -> lexicographic (d2, idx) per-lane min.
//   tau = 16th-smallest of the 64 per-lane-min keys (u64 bitonic sort) ->
//         provable upper bound on the true 16th-smallest key.
//   Pass 2: recompute d2 with the IDENTICAL fmaf chain; collect keys <= tau
//           (expected ~20 per query) into per-query LDS lists.
//   Final: bitonic-sort collected keys, emit smallest 16.
//   QW=2 queries/wave, grid 1024 blocks -> 4 blocks/CU (LDS-limited), 50% occ.
// ---------------------------------------------------------------------------
#define QW   2          // queries per wave
#define CAP  96         // collect capacity per query
#define TILE 2048       // candidates staged per LDS tile

__device__ __forceinline__ u64 bitonic64(u64 v, const int lane) {
    #pragma unroll
    for (int k = 2; k <= 64; k <<= 1) {
        #pragma unroll
        for (int j = k >> 1; j > 0; j >>= 1) {
            const u64  o       = __shfl_xor(v, j);
            const bool up      = ((lane & k) == 0);
            const bool lower   = ((lane & j) == 0);
            const bool takemin = (lower == up);
            const bool sw      = ((o < v) == takemin);
            v = sw ? o : v;
        }
    }
    return v;   // ascending by lane
}

__device__ __forceinline__ float make_d2(const float4 c, const float m2x, const float m2y,
                                         const float m2z, const float qb) {
    float d2 = fmaf(m2x, c.x, fmaf(m2y, c.y, fmaf(m2z, c.z, c.w + qb)));
    return fmaxf(d2, 0.0f);
}

__global__ __launch_bounds__(256) void knn_kernel(const float4* __restrict__ c4,
                                                  int* __restrict__ oidx,
                                                  float* __restrict__ od2) {
    __shared__ float4 s_pt[TILE];            // 32 KB
    __shared__ u64    s_col[4][QW][CAP];     // 6 KB
    __shared__ int    s_cnt[4][QW];

    const int t     = threadIdx.x;
    const int wave  = t >> 6;
    const int lane  = t & 63;
    const int qbase = (blockIdx.x * 4 + wave) * QW;

    // query constants (wave-uniform per qi)
    float m2x[QW], m2y[QW], m2z[QW], qb[QW];
    #pragma unroll
    for (int qi = 0; qi < QW; ++qi) {
        const float4 q = c4[qbase + qi];
        m2x[qi] = -2.0f * q.x;
        m2y[qi] = -2.0f * q.y;
        m2z[qi] = -2.0f * q.z;
        qb[qi]  = q.w;
    }

    if (lane < QW) s_cnt[wave][lane] = 0;    // synced by first staging barrier

    // ---- pass 1: per-lane (d2, idx) minima, float compare ----
    float bd[QW];
    int   bi[QW];
    #pragma unroll
    for (int qi = 0; qi < QW; ++qi) { bd[qi] = 3.0e38f; bi[qi] = 0; }

    for (int tb = 0; tb < NPTS; tb += TILE) {
        __syncthreads();
        for (int jj = t; jj < TILE; jj += 256) s_pt[jj] = c4[tb + jj];
        __syncthreads();
        for (int l = lane; l < TILE; l += 128) {
            const float4 c0 = s_pt[l];
            const float4 c1 = s_pt[l + 64];
            const int j0 = tb + l, j1 = tb + l + 64;
            #pragma unroll
            for (int qi = 0; qi < QW; ++qi) {
                const float d0 = make_d2(c0, m2x[qi], m2y[qi], m2z[qi], qb[qi]);
                const float d1 = make_d2(c1, m2x[qi], m2y[qi], m2z[qi], qb[qi]);
                if (d0 < bd[qi]) { bd[qi] = d0; bi[qi] = j0; }
                if (d1 < bd[qi]) { bd[qi] = d1; bi[qi] = j1; }
            }
        }
    }

    // ---- tau = 16th smallest lane-min key ----
    float tauf[QW]; unsigned taui[QW];
    #pragma unroll
    for (int qi = 0; qi < QW; ++qi) {
        u64 key = ((u64)__float_as_uint(bd[qi]) << 32) | (u64)(unsigned)bi[qi];
        key = bitonic64(key, lane);
        const u64 tk = __shfl(key, 15);
        tauf[qi] = __uint_as_float((unsigned)(tk >> 32));
        taui[qi] = (unsigned)(tk & 0xffffffffu);
    }

    // ---- pass 2: collect keys <= tau (lexicographic) ----
    for (int tb = 0; tb < NPTS; tb += TILE) {
        __syncthreads();
        for (int jj = t; jj < TILE; jj += 256) s_pt[jj] = c4[tb + jj];
        __syncthreads();
        for (int l = lane; l < TILE; l += 128) {
            const float4 c0 = s_pt[l];
            const float4 c1 = s_pt[l + 64];
            const int j0 = tb + l, j1 = tb + l + 64;
            #pragma unroll
            for (int qi = 0; qi < QW; ++qi) {
                const float d0 = make_d2(c0, m2x[qi], m2y[qi], m2z[qi], qb[qi]);
                const float d1 = make_d2(c1, m2x[qi], m2y[qi], m2z[qi], qb[qi]);
                if (d0 < tauf[qi] || (d0 == tauf[qi] && (unsigned)j0 <= taui[qi])) {
                    const int pos = atomicAdd(&s_cnt[wave][qi], 1);
                    if (pos < CAP)
                        s_col[wave][qi][pos] = ((u64)__float_as_uint(d0) << 32) | (u64)(unsigned)j0;
                }
                if (d1 < tauf[qi] || (d1 == tauf[qi] && (unsigned)j1 <= taui[qi])) {
                    const int pos = atomicAdd(&s_cnt[wave][qi], 1);
                    if (pos < CAP)
                        s_col[wave][qi][pos] = ((u64)__float_as_uint(d1) << 32) | (u64)(unsigned)j1;
                }
            }
        }
    }
    __syncthreads();

    // ---- final select per query ----
    #pragma unroll 1
    for (int qi = 0; qi < QW; ++qi) {
        const int q = qbase + qi;
        const int M = s_cnt[wave][qi];
        if (M <= 64) {
            u64 v = (lane < M) ? s_col[wave][qi][lane] : ~0ull;
            v = bitonic64(v, lane);
            if (lane < KNN) {
                oidx[q * KNN + lane] = (int)(v & 0xffffffffu);
                od2 [q * KNN + lane] = __uint_as_float((unsigned)(v >> 32));
            }
        } else {
            // extremely rare fallback: iterative extraction over up to CAP entries
            const int Mc = (M < CAP) ? M : CAP;
            u64 e0 = (lane      < Mc) ? s_col[wave][qi][lane]      : ~0ull;
            u64 e1 = (lane + 64 < Mc) ? s_col[wave][qi][lane + 64] : ~0ull;
            for (int r = 0; r < KNN; ++r) {
                const u64 loc = (e0 < e1) ? e0 : e1;
                u64 g = loc;
                #pragma unroll
                for (int mk = 32; mk >= 1; mk >>= 1) {
                    const u64 o = __shfl_xor(g, mk);
                    g = (o < g) ? o : g;
                }
                if (loc == g) { if (e0 == g) e0 = ~0ull; else e1 = ~0ull; }
                if (lane == 0) {
                    oidx[q * KNN + r] = (int)(g & 0xffffffffu);
                    od2 [q * KNN + r] = __uint_as_float((unsigned)(g >> 32));
                }
            }
        }
    }
}

// ---------------------------------------------------------------------------
// Kernel B: three fp32 GEMMs  xq/xk/xv = x @ W + b     (8192 x 128 x 128)
// ---------------------------------------------------------------------------
__global__ __launch_bounds__(256) void gemm3_kernel(
    const float* __restrict__ x,
    const float* __restrict__ Wq, const float* __restrict__ bq,
    const float* __restrict__ Wk, const float* __restrict__ bk,
    const float* __restrict__ Wv, const float* __restrict__ bv,
    float* __restrict__ xq, float* __restrict__ xk, float* __restrict__ xv) {
    const int which = blockIdx.z;
    const float* W    = (which == 0) ? Wq : (which == 1) ? Wk : Wv;
    const float* bias = (which == 0) ? bq : (which == 1) ? bk : bv;
    float*       out  = (which == 0) ? xq : (which == 1) ? xk : xv;

    const int row0 = blockIdx.x * 64;
    const int col0 = blockIdx.y * 64;

    __shared__ float As[64][68];
    __shared__ float Bs[64][68];

    const int t  = threadIdx.x;
    const int lr = t >> 4;
    const int lc = t & 15;
    const int or0 = (t >> 4) * 4;
    const int oc0 = (t & 15) * 4;

    float acc[4][4] = {};

    for (int kk = 0; kk < CCH; kk += 64) {
        __syncthreads();
        #pragma unroll
        for (int i = 0; i < 4; ++i) {
            const int r = lr + i * 16;
            *(float4*)&As[r][lc * 4] =
                *(const float4*)&x[(size_t)(row0 + r) * CCH + kk + lc * 4];
            *(float4*)&Bs[r][lc * 4] =
                *(const float4*)&W[(size_t)(kk + r) * CCH + col0 + lc * 4];
        }
        __syncthreads();
        #pragma unroll 8
        for (int k = 0; k < 64; ++k) {
            const float a0 = As[or0 + 0][k];
            const float a1 = As[or0 + 1][k];
            const float a2 = As[or0 + 2][k];
            const float a3 = As[or0 + 3][k];
            const float4 b = *(const float4*)&Bs[k][oc0];
            acc[0][0] += a0 * b.x; acc[0][1] += a0 * b.y; acc[0][2] += a0 * b.z; acc[0][3] += a0 * b.w;
            acc[1][0] += a1 * b.x; acc[1][1] += a1 * b.y; acc[1][2] += a1 * b.z; acc[1][3] += a1 * b.w;
            acc[2][0] += a2 * b.x; acc[2][1] += a2 * b.y; acc[2][2] += a2 * b.z; acc[2][3] += a2 * b.w;
            acc[3][0] += a3 * b.x; acc[3][1] += a3 * b.y; acc[3][2] += a3 * b.z; acc[3][3] += a3 * b.w;
        }
    }

    const float4 bb = *(const float4*)&bias[col0 + oc0];
    #pragma unroll
    for (int i = 0; i < 4; ++i) {
        const int r = row0 + or0 + i;
        float4 o;
        o.x = acc[i][0] + bb.x;
        o.y = acc[i][1] + bb.y;
        o.z = acc[i][2] + bb.z;
        o.w = acc[i][3] + bb.w;
        *(float4*)&out[(size_t)r * CCH + col0 + oc0] = o;
    }
}

// ---------------------------------------------------------------------------
// Kernel C: fused per-point attention.  1 block (256 thr) = 1 query point.
// ---------------------------------------------------------------------------
#define LD8(dst, arr) do { \
    const float4 _a = *(const float4*)&(arr)[c0];     \
    const float4 _b = *(const float4*)&(arr)[c0 + 4]; \
    dst[0] = _a.x; dst[1] = _a.y; dst[2] = _a.z; dst[3] = _a.w; \
    dst[4] = _b.x; dst[5] = _b.y; dst[6] = _b.z; dst[7] = _b.w; } while (0)

__global__ __launch_bounds__(256) void fused_kernel(
    const float* __restrict__ p,
    const float* __restrict__ xqg, const float* __restrict__ xkg, const float* __restrict__ xvg,
    const int* __restrict__ nidx, const float* __restrict__ nd2,
    const float* __restrict__ Wp1, const float* __restrict__ bp1,
    const float* __restrict__ g1,  const float* __restrict__ be1,
    const float* __restrict__ Wp2, const float* __restrict__ bp2,
    const float* __restrict__ g2,  const float* __restrict__ be2,
    const float* __restrict__ Ww1, const float* __restrict__ bw1,
    const float* __restrict__ g3,  const float* __restrict__ be3,
    const float* __restrict__ Ww2, const float* __restrict__ bw2,
    float* __restrict__ out) {
    const int i = blockIdx.x;
    const int t = threadIdx.x;

    __shared__ float s_wv[16][132];
    __shared__ float s_val[16][132];
    __shared__ float s_w1t[16][132];   // Ww1 transposed: [m][c]
    __shared__ float s_wp2[3][128];
    __shared__ float s_bp2[128], s_g2s[128], s_be2[128], s_xq[128];
    __shared__ float s_r[16][17], s_w2[16][17], s_e[16][17], s_wn[16][17];
    __shared__ float s_ww2[256];       // [mm][m] row-major
    __shared__ float s_sm[64];         // bw1 | g3*rs | be3 | bw2

    if (t < 128) {
        const int c = t;
        s_wp2[0][c] = Wp2[c];
        s_wp2[1][c] = Wp2[128 + c];
        s_wp2[2][c] = Wp2[256 + c];
        s_bp2[c]    = bp2[c];
        s_g2s[c]    = g2[c] * BN_RS;
        s_be2[c]    = be2[c];
        s_xq[c]     = xqg[(size_t)i * CCH + c];
    } else {
        const int u = t - 128;
        if (u < 16)      s_sm[u] = bw1[u];
        else if (u < 32) s_sm[u] = g3[u - 16] * BN_RS;
        else if (u < 48) s_sm[u] = be3[u - 32];
        else if (u < 64) s_sm[u] = bw2[u - 48];
    }
    s_ww2[t] = Ww2[t];
    #pragma unroll
    for (int e = t; e < 2048; e += 256) s_w1t[e & 15][e >> 4] = Ww1[e];
    __syncthreads();

    // ---- phase 1 ----
    const int k  = t >> 4;
    const int tl = t & 15;
    const int c0 = tl * 8;

    const int   jn  = nidx[i * KNN + k];
    const float d2v = nd2[i * KNN + k];
    const float dw  = expf(-sqrtf(fmaxf(d2v, 0.f)));

    const float prx = p[jn * 3 + 0] - p[i * 3 + 0];
    const float pry = p[jn * 3 + 1] - p[i * 3 + 1];
    const float prz = p[jn * 3 + 2] - p[i * 3 + 2];
    float tt[3];
    #pragma unroll
    for (int e = 0; e < 3; ++e) {
        float v = prx * Wp1[0 * 3 + e] + pry * Wp1[1 * 3 + e] + prz * Wp1[2 * 3 + e] + bp1[e];
        v = v * (g1[e] * BN_RS) + be1[e];
        tt[e] = fmaxf(v, 0.f);
    }

    {
        const float4 a0 = *(const float4*)&xkg[(size_t)jn * CCH + c0];
        const float4 a1 = *(const float4*)&xkg[(size_t)jn * CCH + c0 + 4];
        const float4 b0 = *(const float4*)&xvg[(size_t)jn * CCH + c0];
        const float4 b1 = *(const float4*)&xvg[(size_t)jn * CCH + c0 + 4];
        const float xk8[8] = {a0.x, a0.y, a0.z, a0.w, a1.x, a1.y, a1.z, a1.w};
        const float xv8[8] = {b0.x, b0.y, b0.z, b0.w, b1.x, b1.y, b1.z, b1.w};
        float w08[8], w18[8], w28[8], bp8[8], xq8[8], gs8[8], bb8[8];
        LD8(w08, s_wp2[0]); LD8(w18, s_wp2[1]); LD8(w28, s_wp2[2]);
        LD8(bp8, s_bp2); LD8(xq8, s_xq); LD8(gs8, s_g2s); LD8(bb8, s_be2);
        float wv8[8], val8[8];
        #pragma unroll
        for (int d = 0; d < 8; ++d) {
            const float pr = tt[0] * w08[d] + tt[1] * w18[d] + tt[2] * w28[d] + bp8[d];
            float wvv = (xq8[d] - xk8[d]) + pr;
            wvv = fmaxf(wvv * gs8[d] + bb8[d], 0.f);
            wv8[d]  = wvv;
            val8[d] = xv8[d] * dw + pr;
        }
        *(float4*)&s_wv [k][c0]     = make_float4(wv8[0], wv8[1], wv8[2], wv8[3]);
        *(float4*)&s_wv [k][c0 + 4] = make_float4(wv8[4], wv8[5], wv8[6], wv8[7]);
        *(float4*)&s_val[k][c0]     = make_float4(val8[0], val8[1], val8[2], val8[3]);
        *(float4*)&s_val[k][c0 + 4] = make_float4(val8[4], val8[5], val8[6], val8[7]);
    }
    __syncthreads();

    // ---- phase 2 ----
    const int k2 = t >> 4, m = t & 15;
    float acc = s_sm[m];
    #pragma unroll
    for (int c = 0; c < CCH; c += 4) {
        const float4 a = *(const float4*)&s_wv[k2][c];
        const float4 b = *(const float4*)&s_w1t[m][c];
        acc += a.x * b.x; acc += a.y * b.y; acc += a.z * b.z; acc += a.w * b.w;
    }
    const float rr = fmaxf(acc * s_sm[16 + m] + s_sm[32 + m], 0.f);
    s_r[k2][m] = rr;
    __syncthreads();

    float acc2 = s_sm[48 + m];
    #pragma unroll
    for (int mm = 0; mm < 16; ++mm) acc2 += s_r[k2][mm] * s_ww2[mm * 16 + m];
    s_w2[k2][m] = acc2;
    __syncthreads();

    // ---- phase 3: softmax over k ----
    float mx = s_w2[0][m];
    #pragma unroll
    for (int kk = 1; kk < 16; ++kk) mx = fmaxf(mx, s_w2[kk][m]);
    const float ev = expf(acc2 - mx);
    s_e[k2][m] = ev;
    __syncthreads();
    float ssum = 0.f;
    #pragma unroll
    for (int kk = 0; kk < 16; ++kk) ssum += s_e[kk][m];
    s_wn[k2][m] = ev / ssum;
    __syncthreads();

    // ---- phase 4 ----
    if (t < 128) {
        const int c = t, mc = t & 15;
        float o = 0.f;
        #pragma unroll
        for (int kk = 0; kk < 16; ++kk) o += s_val[kk][c] * s_wn[kk][mc];
        out[(size_t)i * CCH + c] = o;
    }
}

// ---------------------------------------------------------------------------
extern "C" void kernel_launch(void* const* d_in, const int* in_sizes, int n_in,
                              void* d_out, int out_size, void* d_ws, size_t ws_size,
                              hipStream_t stream) {
    (void)in_sizes; (void)n_in; (void)out_size; (void)ws_size;
    const float* p   = (const float*)d_in[0];
    const float* x   = (const float*)d_in[1];
    const float* Wq  = (const float*)d_in[2];
    const float* bq  = (const float*)d_in[3];
    const float* Wk  = (const float*)d_in[4];
    const float* bk  = (const float*)d_in[5];
    const float* Wv  = (const float*)d_in[6];
    const float* bv  = (const float*)d_in[7];
    const float* Wp1 = (const float*)d_in[8];
    const float* bp1 = (const float*)d_in[9];
    const float* g1  = (const float*)d_in[10];
    const float* be1 = (const float*)d_in[11];
    const float* Wp2 = (const float*)d_in[12];
    const float* bp2 = (const float*)d_in[13];
    const float* g2  = (const float*)d_in[14];
    const float* be2 = (const float*)d_in[15];
    const float* Ww1 = (const float*)d_in[16];
    const float* bw1 = (const float*)d_in[17];
    const float* g3  = (const float*)d_in[18];
    const float* be3 = (const float*)d_in[19];
    const float* Ww2 = (const float*)d_in[20];
    const float* bw2 = (const float*)d_in[21];
    float* out = (float*)d_out;

    // workspace layout
    char* ws = (char*)d_ws;
    int*    idxb = (int*)ws;                                   // 512 KB
    float*  d2b  = (float*)(ws + (size_t)512 * 1024);          // 512 KB
    float*  xqb  = (float*)(ws + (size_t)1 * 1024 * 1024);     // 4 MB
    float*  xkb  = (float*)(ws + (size_t)5 * 1024 * 1024);     // 4 MB
    float*  xvb  = (float*)(ws + (size_t)9 * 1024 * 1024);     // 4 MB
    float4* c4b  = (float4*)(ws + (size_t)13 * 1024 * 1024);   // 128 KB

    pack_kernel<<<dim3(NPTS / 256), dim3(256), 0, stream>>>(p, c4b);
    knn_kernel<<<dim3(NPTS / (4 * QW)), dim3(256), 0, stream>>>(c4b, idxb, d2b);
    gemm3_kernel<<<dim3(NPTS / 64, CCH / 64, 3), dim3(256), 0, stream>>>(
        x, Wq, bq, Wk, bk, Wv, bv, xqb, xkb, xvb);
    fused_kernel<<<dim3(NPTS), dim3(256), 0, stream>>>(
        p, xqb, xkb, xvb, idxb, d2b,
        Wp1, bp1, g1, be1, Wp2, bp2, g2, be2, Ww1, bw1, g3, be3, Ww2, bw2, out);
}

// Round 4
// 118.987 us; speedup vs baseline: 12.2553x; 1.0835x over previous
//
#include <hip/hip_runtime.h>
#include <math.h>

// Problem constants (fixed-shape problem)
#define NPTS 8192
#define CCH  128
#define KNN  16
#define BN_RS 0.9999950000374997f   // 1/sqrt(1 + 1e-5)

typedef unsigned long long u64;

// ---------------------------------------------------------------------------
// Kernel P: pack candidate points as float4 (x, y, z, |p|^2)
// ---------------------------------------------------------------------------
__global__ __launch_bounds__(256) void pack_kernel(const float* __restrict__ p,
                                                   float4* __restrict__ c4) {
    const int j = blockIdx.x * 256 + threadIdx.x;
    if (j < NPTS) {
        const float x = p[3 * j + 0], y = p[3 * j + 1], z = p[3 * j + 2];
        c4[j] = make_float4(x, y, z, x * x + y * y + z * z);
    }
}

// ---------------------------------------------------------------------------
// Kernel A: KNN via sampled-threshold 1.25-pass select.
//   Phase A (global, barrier-free): per-lane float min over its 1/64 subset of
//     the FIRST 4096 candidates. tau = 16th-smallest of the 64 lane minima
//     (bitonic float sort). The 16 lane-mins <= tau are 16 distinct candidates
//     => tau >= true 16th-smallest d2 over the full set (provable upper bound).
//   Phase B: one pass over all 8192 (LDS tiles): collect u64 keys
//     (d2bits<<32|idx) with d2 <= tau. E[M]~37, CAP=104.
//   Final: bitonic sort (1 or 2 blocks) -> 16 smallest keys = exact
//     lexicographic (d2, idx) top-k (matches jax top_k tie-breaks).
//   Overflow (M>CAP, ~never): exact fallback — full lane-min -> tight tau ->
//     re-collect from global (E~18 << CAP).
// ---------------------------------------------------------------------------
#define QW    2          // queries per wave
#define CAP   104        // collect capacity per query
#define TILE  2048       // candidates staged per LDS tile
#define SAMPN 4096       // phase-A sample count

__device__ __forceinline__ u64 bitonic64(u64 v, const int lane) {
    #pragma unroll
    for (int k = 2; k <= 64; k <<= 1) {
        #pragma unroll
        for (int j = k >> 1; j > 0; j >>= 1) {
            const u64  o       = __shfl_xor(v, j);
            const bool takemin = (((lane & j) == 0) == ((lane & k) == 0));
            v = ((o < v) == takemin) ? o : v;
        }
    }
    return v;   // ascending by lane
}

__device__ __forceinline__ float bitonicf(float v, const int lane) {
    #pragma unroll
    for (int k = 2; k <= 64; k <<= 1) {
        #pragma unroll
        for (int j = k >> 1; j > 0; j >>= 1) {
            const float o      = __shfl_xor(v, j);
            const bool takemin = (((lane & j) == 0) == ((lane & k) == 0));
            v = ((o < v) == takemin) ? o : v;
        }
    }
    return v;   // ascending by lane
}

__device__ __forceinline__ float make_d2(const float4 c, const float m2x, const float m2y,
                                         const float m2z, const float qb) {
    float d2 = fmaf(m2x, c.x, fmaf(m2y, c.y, fmaf(m2z, c.z, c.w + qb)));
    return fmaxf(d2, 0.0f);   // clamp essential: keeps u64 key order correct at d2~0
}

__global__ __launch_bounds__(256) void knn_kernel(const float4* __restrict__ c4,
                                                  int* __restrict__ oidx,
                                                  float* __restrict__ od2) {
    __shared__ float4 s_pt[TILE];            // 32 KB
    __shared__ u64    s_col[4][QW][CAP];     // 6.5 KB
    __shared__ int    s_cnt[4][QW];

    const int t     = threadIdx.x;
    const int wave  = t >> 6;
    const int lane  = t & 63;
    const int qbase = (blockIdx.x * 4 + wave) * QW;

    float m2x[QW], m2y[QW], m2z[QW], qb[QW];
    #pragma unroll
    for (int qi = 0; qi < QW; ++qi) {
        const float4 q = c4[qbase + qi];
        m2x[qi] = -2.0f * q.x;
        m2y[qi] = -2.0f * q.y;
        m2z[qi] = -2.0f * q.z;
        qb[qi]  = q.w;
    }
    if (lane < QW) s_cnt[wave][lane] = 0;    // synced by first staging barrier

    // ---- phase A: lane minima over first SAMPN candidates (global/L2) ----
    float bd[QW];
    #pragma unroll
    for (int qi = 0; qi < QW; ++qi) bd[qi] = 3.0e38f;

    for (int l = lane; l < SAMPN; l += 128) {
        const float4 c0 = c4[l];
        const float4 c1 = c4[l + 64];
        #pragma unroll
        for (int qi = 0; qi < QW; ++qi) {
            const float d0 = make_d2(c0, m2x[qi], m2y[qi], m2z[qi], qb[qi]);
            const float d1 = make_d2(c1, m2x[qi], m2y[qi], m2z[qi], qb[qi]);
            bd[qi] = fminf(bd[qi], fminf(d0, d1));
        }
    }

    float tauf[QW];
    #pragma unroll
    for (int qi = 0; qi < QW; ++qi) {
        const float s = bitonicf(bd[qi], lane);
        tauf[qi] = __shfl(s, 15);
    }

    // ---- phase B: single collect pass over LDS tiles ----
    for (int tb = 0; tb < NPTS; tb += TILE) {
        __syncthreads();
        for (int jj = t; jj < TILE; jj += 256) s_pt[jj] = c4[tb + jj];
        __syncthreads();
        for (int l = lane; l < TILE; l += 128) {
            const float4 c0 = s_pt[l];
            const float4 c1 = s_pt[l + 64];
            const int j0 = tb + l, j1 = tb + l + 64;
            #pragma unroll
            for (int qi = 0; qi < QW; ++qi) {
                const float d0 = make_d2(c0, m2x[qi], m2y[qi], m2z[qi], qb[qi]);
                const float d1 = make_d2(c1, m2x[qi], m2y[qi], m2z[qi], qb[qi]);
                if (d0 <= tauf[qi]) {
                    const int pos = atomicAdd(&s_cnt[wave][qi], 1);
                    if (pos < CAP)
                        s_col[wave][qi][pos] = ((u64)__float_as_uint(d0) << 32) | (u64)(unsigned)j0;
                }
                if (d1 <= tauf[qi]) {
                    const int pos = atomicAdd(&s_cnt[wave][qi], 1);
                    if (pos < CAP)
                        s_col[wave][qi][pos] = ((u64)__float_as_uint(d1) << 32) | (u64)(unsigned)j1;
                }
            }
        }
    }
    // no further barrier needed: s_col/s_cnt are wave-private, LDS is in-order

    // ---- final select per query ----
    #pragma unroll 1
    for (int qi = 0; qi < QW; ++qi) {
        const int q = qbase + qi;
        int M = s_cnt[wave][qi];

        if (M > CAP) {
            // exact fallback (exercised ~never): tight tau from FULL lane-min
            float fb = 3.0e38f;
            for (int l = lane; l < NPTS; l += 64)
                fb = fminf(fb, make_d2(c4[l], m2x[qi], m2y[qi], m2z[qi], qb[qi]));
            const float s    = bitonicf(fb, lane);
            const float tau2 = __shfl(s, 15);
            if (lane == 0) s_cnt[wave][qi] = 0;   // wave-internal, LDS in-order
            for (int l = lane; l < NPTS; l += 64) {
                const float d = make_d2(c4[l], m2x[qi], m2y[qi], m2z[qi], qb[qi]);
                if (d <= tau2) {
                    const int pos = atomicAdd(&s_cnt[wave][qi], 1);
                    if (pos < CAP)
                        s_col[wave][qi][pos] = ((u64)__float_as_uint(d) << 32) | (u64)(unsigned)l;
                }
            }
            M = s_cnt[wave][qi];
            if (M > CAP) M = CAP;   // unreachable for non-degenerate data
        }

        if (M <= 64) {
            u64 v = (lane < M) ? s_col[wave][qi][lane] : ~0ull;
            v = bitonic64(v, lane);
            if (lane < KNN) {
                oidx[q * KNN + lane] = (int)(v & 0xffffffffu);
                od2 [q * KNN + lane] = __uint_as_float((unsigned)(v >> 32));
            }
        } else {
            // top-16 of union = top-16( top16(A) U top16(B) )
            u64 a = (lane < 64) ? s_col[wave][qi][lane] : ~0ull;
            if (lane >= M) a = ~0ull;
            a = bitonic64(a, lane);
            u64 b = (lane + 64 < M) ? s_col[wave][qi][lane + 64] : ~0ull;
            b = bitonic64(b, lane);
            const u64 bs = __shfl(b, lane & 15);
            u64 mv = (lane < 16) ? a : ((lane < 32) ? bs : ~0ull);
            mv = bitonic64(mv, lane);
            if (lane < KNN) {
                oidx[q * KNN + lane] = (int)(mv & 0xffffffffu);
                od2 [q * KNN + lane] = __uint_as_float((unsigned)(mv >> 32));
            }
        }
    }
}

// ---------------------------------------------------------------------------
// Kernel B: three fp32 GEMMs  xq/xk/xv = x @ W + b     (8192 x 128 x 128)
// ---------------------------------------------------------------------------
__global__ __launch_bounds__(256) void gemm3_kernel(
    const float* __restrict__ x,
    const float* __restrict__ Wq, const float* __restrict__ bq,
    const float* __restrict__ Wk, const float* __restrict__ bk,
    const float* __restrict__ Wv, const float* __restrict__ bv,
    float* __restrict__ xq, float* __restrict__ xk, float* __restrict__ xv) {
    const int which = blockIdx.z;
    const float* W    = (which == 0) ? Wq : (which == 1) ? Wk : Wv;
    const float* bias = (which == 0) ? bq : (which == 1) ? bk : bv;
    float*       out  = (which == 0) ? xq : (which == 1) ? xk : xv;

    const int row0 = blockIdx.x * 64;
    const int col0 = blockIdx.y * 64;

    __shared__ float As[64][68];
    __shared__ float Bs[64][68];

    const int t  = threadIdx.x;
    const int lr = t >> 4;
    const int lc = t & 15;
    const int or0 = (t >> 4) * 4;
    const int oc0 = (t & 15) * 4;

    float acc[4][4] = {};

    for (int kk = 0; kk < CCH; kk += 64) {
        __syncthreads();
        #pragma unroll
        for (int i = 0; i < 4; ++i) {
            const int r = lr + i * 16;
            *(float4*)&As[r][lc * 4] =
                *(const float4*)&x[(size_t)(row0 + r) * CCH + kk + lc * 4];
            *(float4*)&Bs[r][lc * 4] =
                *(const float4*)&W[(size_t)(kk + r) * CCH + col0 + lc * 4];
        }
        __syncthreads();
        #pragma unroll 8
        for (int k = 0; k < 64; ++k) {
            const float a0 = As[or0 + 0][k];
            const float a1 = As[or0 + 1][k];
            const float a2 = As[or0 + 2][k];
            const float a3 = As[or0 + 3][k];
            const float4 b = *(const float4*)&Bs[k][oc0];
            acc[0][0] += a0 * b.x; acc[0][1] += a0 * b.y; acc[0][2] += a0 * b.z; acc[0][3] += a0 * b.w;
            acc[1][0] += a1 * b.x; acc[1][1] += a1 * b.y; acc[1][2] += a1 * b.z; acc[1][3] += a1 * b.w;
            acc[2][0] += a2 * b.x; acc[2][1] += a2 * b.y; acc[2][2] += a2 * b.z; acc[2][3] += a2 * b.w;
            acc[3][0] += a3 * b.x; acc[3][1] += a3 * b.y; acc[3][2] += a3 * b.z; acc[3][3] += a3 * b.w;
        }
    }

    const float4 bb = *(const float4*)&bias[col0 + oc0];
    #pragma unroll
    for (int i = 0; i < 4; ++i) {
        const int r = row0 + or0 + i;
        float4 o;
        o.x = acc[i][0] + bb.x;
        o.y = acc[i][1] + bb.y;
        o.z = acc[i][2] + bb.z;
        o.w = acc[i][3] + bb.w;
        *(float4*)&out[(size_t)r * CCH + col0 + oc0] = o;
    }
}

// ---------------------------------------------------------------------------
// Kernel C: fused per-point attention.  1 block (256 thr) = 1 query point.
// Phase 2 rewritten: wv stays in registers from phase 1 (thread (k,tl) holds
// wv[k][tl*8..+7]); each lane computes partials p[m] for ALL 16 m against a
// half-split W1T LDS layout (2-way/free b128 reads), then a 15-shuffle
// butterfly transpose-reduce lands w1[k][m] at lane (k,m). s_wv eliminated.
// ---------------------------------------------------------------------------
#define LD8(dst, arr) do { \
    const float4 _a = *(const float4*)&(arr)[c0];     \
    const float4 _b = *(const float4*)&(arr)[c0 + 4]; \
    dst[0] = _a.x; dst[1] = _a.y; dst[2] = _a.z; dst[3] = _a.w; \
    dst[4] = _b.x; dst[5] = _b.y; dst[6] = _b.z; dst[7] = _b.w; } while (0)

__global__ __launch_bounds__(256) void fused_kernel(
    const float* __restrict__ p,
    const float* __restrict__ xqg, const float* __restrict__ xkg, const float* __restrict__ xvg,
    const int* __restrict__ nidx, const float* __restrict__ nd2,
    const float* __restrict__ Wp1, const float* __restrict__ bp1,
    const float* __restrict__ g1,  const float* __restrict__ be1,
    const float* __restrict__ Wp2, const float* __restrict__ bp2,
    const float* __restrict__ g2,  const float* __restrict__ be2,
    const float* __restrict__ Ww1, const float* __restrict__ bw1,
    const float* __restrict__ g3,  const float* __restrict__ be3,
    const float* __restrict__ Ww2, const float* __restrict__ bw2,
    float* __restrict__ out) {
    const int i = blockIdx.x;
    const int t = threadIdx.x;

    __shared__ float s_val[16][132];
    __shared__ float s_w1tA[16][64];   // W1T halves: A[m][tl*4+e] = Ww1[(8tl+e)*16+m], e<4
    __shared__ float s_w1tB[16][64];   //             B[m][tl*4+e] = Ww1[(8tl+e+4)*16+m]
    __shared__ float s_wp2[3][128];
    __shared__ float s_bp2[128], s_g2s[128], s_be2[128], s_xq[128];
    __shared__ float s_r[16][17], s_w2[16][17], s_e[16][17], s_wn[16][17];
    __shared__ float s_ww2[256];       // [mm][m] row-major
    __shared__ float s_sm[64];         // bw1 | g3*rs | be3 | bw2

    if (t < 128) {
        const int c = t;
        s_wp2[0][c] = Wp2[c];
        s_wp2[1][c] = Wp2[128 + c];
        s_wp2[2][c] = Wp2[256 + c];
        s_bp2[c]    = bp2[c];
        s_g2s[c]    = g2[c] * BN_RS;
        s_be2[c]    = be2[c];
        s_xq[c]     = xqg[(size_t)i * CCH + c];
    } else {
        const int u = t - 128;
        if (u < 16)      s_sm[u] = bw1[u];
        else if (u < 32) s_sm[u] = g3[u - 16] * BN_RS;
        else if (u < 48) s_sm[u] = be3[u - 32];
        else if (u < 64) s_sm[u] = bw2[u - 48];
    }
    s_ww2[t] = Ww2[t];
    #pragma unroll
    for (int e2 = t; e2 < 2048; e2 += 256) {
        const int m = e2 & 15, c = e2 >> 4;
        const int tl8 = c >> 3, e = c & 7;
        const float v = Ww1[e2];
        if (e < 4) s_w1tA[m][tl8 * 4 + e]       = v;
        else       s_w1tB[m][tl8 * 4 + (e - 4)] = v;
    }
    __syncthreads();

    // ---- phase 1: gather + pr + wv (registers) + val (LDS) ----
    const int k  = t >> 4;
    const int tl = t & 15;
    const int c0 = tl * 8;

    const int   jn  = nidx[i * KNN + k];
    const float d2v = nd2[i * KNN + k];
    const float dw  = expf(-sqrtf(fmaxf(d2v, 0.f)));

    const float prx = p[jn * 3 + 0] - p[i * 3 + 0];
    const float pry = p[jn * 3 + 1] - p[i * 3 + 1];
    const float prz = p[jn * 3 + 2] - p[i * 3 + 2];
    float tt[3];
    #pragma unroll
    for (int e = 0; e < 3; ++e) {
        float v = prx * Wp1[0 * 3 + e] + pry * Wp1[1 * 3 + e] + prz * Wp1[2 * 3 + e] + bp1[e];
        v = v * (g1[e] * BN_RS) + be1[e];
        tt[e] = fmaxf(v, 0.f);
    }

    float wv8[8];
    {
        const float4 a0 = *(const float4*)&xkg[(size_t)jn * CCH + c0];
        const float4 a1 = *(const float4*)&xkg[(size_t)jn * CCH + c0 + 4];
        const float4 b0 = *(const float4*)&xvg[(size_t)jn * CCH + c0];
        const float4 b1 = *(const float4*)&xvg[(size_t)jn * CCH + c0 + 4];
        const float xk8[8] = {a0.x, a0.y, a0.z, a0.w, a1.x, a1.y, a1.z, a1.w};
        const float xv8[8] = {b0.x, b0.y, b0.z, b0.w, b1.x, b1.y, b1.z, b1.w};
        float w08[8], w18[8], w28[8], bp8[8], xq8[8], gs8[8], bb8[8];
        LD8(w08, s_wp2[0]); LD8(w18, s_wp2[1]); LD8(w28, s_wp2[2]);
        LD8(bp8, s_bp2); LD8(xq8, s_xq); LD8(gs8, s_g2s); LD8(bb8, s_be2);
        float val8[8];
        #pragma unroll
        for (int d = 0; d < 8; ++d) {
            const float pr = tt[0] * w08[d] + tt[1] * w18[d] + tt[2] * w28[d] + bp8[d];
            float wvv = (xq8[d] - xk8[d]) + pr;
            wv8[d]  = fmaxf(wvv * gs8[d] + bb8[d], 0.f);
            val8[d] = xv8[d] * dw + pr;
        }
        *(float4*)&s_val[k][c0]     = make_float4(val8[0], val8[1], val8[2], val8[3]);
        *(float4*)&s_val[k][c0 + 4] = make_float4(val8[4], val8[5], val8[6], val8[7]);
    }
    // no barrier: wv8 is register-local; s_val not read until after s_r barrier

    // ---- phase 2: p[m] partials (all m) then butterfly transpose-reduce ----
    float pp[16];
    #pragma unroll
    for (int m = 0; m < 16; ++m) {
        const float4 a = *(const float4*)&s_w1tA[m][tl * 4];
        const float4 b = *(const float4*)&s_w1tB[m][tl * 4];
        pp[m] = wv8[0] * a.x + wv8[1] * a.y + wv8[2] * a.z + wv8[3] * a.w
              + wv8[4] * b.x + wv8[5] * b.y + wv8[6] * b.z + wv8[7] * b.w;
    }
    float q8[8];
    #pragma unroll
    for (int j = 0; j < 8; ++j) {
        const float send = (tl & 8) ? pp[j] : pp[j + 8];
        const float keep = (tl & 8) ? pp[j + 8] : pp[j];
        q8[j] = keep + __shfl_xor(send, 8);
    }
    float q4[4];
    #pragma unroll
    for (int j = 0; j < 4; ++j) {
        const float send = (tl & 4) ? q8[j] : q8[j + 4];
        const float keep = (tl & 4) ? q8[j + 4] : q8[j];
        q4[j] = keep + __shfl_xor(send, 4);
    }
    float q2[2];
    #pragma unroll
    for (int j = 0; j < 2; ++j) {
        const float send = (tl & 2) ? q4[j] : q4[j + 2];
        const float keep = (tl & 2) ? q4[j + 2] : q4[j];
        q2[j] = keep + __shfl_xor(send, 2);
    }
    const float send1 = (tl & 1) ? q2[0] : q2[1];
    const float keep1 = (tl & 1) ? q2[1] : q2[0];
    const float w1sum = keep1 + __shfl_xor(send1, 1);

    const int m = tl;                       // lane (k, m) now holds w1[k][m]
    const float acc = w1sum + s_sm[m];      // + bw1[m]
    const float rr  = fmaxf(acc * s_sm[16 + m] + s_sm[32 + m], 0.f);
    s_r[k][m] = rr;
    __syncthreads();

    float acc2 = s_sm[48 + m];
    #pragma unroll
    for (int mm = 0; mm < 16; ++mm) acc2 += s_r[k][mm] * s_ww2[mm * 16 + m];
    s_w2[k][m] = acc2;
    __syncthreads();

    // ---- phase 3: softmax over k ----
    float mx = s_w2[0][m];
    #pragma unroll
    for (int kk = 1; kk < 16; ++kk) mx = fmaxf(mx, s_w2[kk][m]);
    const float ev = expf(acc2 - mx);
    s_e[k][m] = ev;
    __syncthreads();
    float ssum = 0.f;
    #pragma unroll
    for (int kk = 0; kk < 16; ++kk) ssum += s_e[kk][m];
    s_wn[k][m] = ev / ssum;
    __syncthreads();

    // ---- phase 4 ----
    if (t < 128) {
        const int c = t, mc = t & 15;
        float o = 0.f;
        #pragma unroll
        for (int kk = 0; kk < 16; ++kk) o += s_val[kk][c] * s_wn[kk][mc];
        out[(size_t)i * CCH + c] = o;
    }
}

// ---------------------------------------------------------------------------
extern "C" void kernel_launch(void* const* d_in, const int* in_sizes, int n_in,
                              void* d_out, int out_size, void* d_ws, size_t ws_size,
                              hipStream_t stream) {
    (void)in_sizes; (void)n_in; (void)out_size; (void)ws_size;
    const float* p   = (const float*)d_in[0];
    const float* x   = (const float*)d_in[1];
    const float* Wq  = (const float*)d_in[2];
    const float* bq  = (const float*)d_in[3];
    const float* Wk  = (const float*)d_in[4];
    const float* bk  = (const float*)d_in[5];
    const float* Wv  = (const float*)d_in[6];
    const float* bv  = (const float*)d_in[7];
    const float* Wp1 = (const float*)d_in[8];
    const float* bp1 = (const float*)d_in[9];
    const float* g1  = (const float*)d_in[10];
    const float* be1 = (const float*)d_in[11];
    const float* Wp2 = (const float*)d_in[12];
    const float* bp2 = (const float*)d_in[13];
    const float* g2  = (const float*)d_in[14];
    const float* be2 = (const float*)d_in[15];
    const float* Ww1 = (const float*)d_in[16];
    const float* bw1 = (const float*)d_in[17];
    const float* g3  = (const float*)d_in[18];
    const float* be3 = (const float*)d_in[19];
    const float* Ww2 = (const float*)d_in[20];
    const float* bw2 = (const float*)d_in[21];
    float* out = (float*)d_out;

    // workspace layout
    char* ws = (char*)d_ws;
    int*    idxb = (int*)ws;                                   // 512 KB
    float*  d2b  = (float*)(ws + (size_t)512 * 1024);          // 512 KB
    float*  xqb  = (float*)(ws + (size_t)1 * 1024 * 1024);     // 4 MB
    float*  xkb  = (float*)(ws + (size_t)5 * 1024 * 1024);     // 4 MB
    float*  xvb  = (float*)(ws + (size_t)9 * 1024 * 1024);     // 4 MB
    float4* c4b  = (float4*)(ws + (size_t)13 * 1024 * 1024);   // 128 KB

    pack_kernel<<<dim3(NPTS / 256), dim3(256), 0, stream>>>(p, c4b);
    knn_kernel<<<dim3(NPTS / (4 * QW)), dim3(256), 0, stream>>>(c4b, idxb, d2b);
    gemm3_kernel<<<dim3(NPTS / 64, CCH / 64, 3), dim3(256), 0, stream>>>(
        x, Wq, bq, Wk, bk, Wv, bv, xqb, xkb, xvb);
    fused_kernel<<<dim3(NPTS), dim3(256), 0, stream>>>(
        p, xqb, xkb, xvb, idxb, d2b,
        Wp1, bp1, g1, be1, Wp2, bp2, g2, be2, Ww1, bw1, g3, be3, Ww2, bw2, out);
}

// Round 5
// 109.851 us; speedup vs baseline: 13.2746x; 1.0832x over previous
//
#include <hip/hip_runtime.h>
#include <math.h>

// Problem constants (fixed-shape problem)
#define NPTS 8192
#define CCH  128
#define KNN  16
#define BN_RS 0.9999950000374997f   // 1/sqrt(1 + 1e-5)

typedef unsigned long long u64;

// ---------------------------------------------------------------------------
// Kernel P: pack candidate points as float4 (x, y, z, |p|^2)
// ---------------------------------------------------------------------------
__global__ __launch_bounds__(256) void pack_kernel(const float* __restrict__ p,
                                                   float4* __restrict__ c4) {
    const int j = blockIdx.x * 256 + threadIdx.x;
    if (j < NPTS) {
        const float x = p[3 * j + 0], y = p[3 * j + 1], z = p[3 * j + 2];
        c4[j] = make_float4(x, y, z, x * x + y * y + z * z);
    }
}

// ---------------------------------------------------------------------------
// Kernel A: KNN via sampled-threshold 1.25-pass select (unchanged from R4).
// ---------------------------------------------------------------------------
#define QW    2
#define CAP   104
#define TILE  2048
#define SAMPN 4096

__device__ __forceinline__ u64 bitonic64(u64 v, const int lane) {
    #pragma unroll
    for (int k = 2; k <= 64; k <<= 1) {
        #pragma unroll
        for (int j = k >> 1; j > 0; j >>= 1) {
            const u64  o       = __shfl_xor(v, j);
            const bool takemin = (((lane & j) == 0) == ((lane & k) == 0));
            v = ((o < v) == takemin) ? o : v;
        }
    }
    return v;
}

__device__ __forceinline__ float bitonicf(float v, const int lane) {
    #pragma unroll
    for (int k = 2; k <= 64; k <<= 1) {
        #pragma unroll
        for (int j = k >> 1; j > 0; j >>= 1) {
            const float o      = __shfl_xor(v, j);
            const bool takemin = (((lane & j) == 0) == ((lane & k) == 0));
            v = ((o < v) == takemin) ? o : v;
        }
    }
    return v;
}

__device__ __forceinline__ float make_d2(const float4 c, const float m2x, const float m2y,
                                         const float m2z, const float qb) {
    float d2 = fmaf(m2x, c.x, fmaf(m2y, c.y, fmaf(m2z, c.z, c.w + qb)));
    return fmaxf(d2, 0.0f);
}

__global__ __launch_bounds__(256) void knn_kernel(const float4* __restrict__ c4,
                                                  int* __restrict__ oidx,
                                                  float* __restrict__ od2) {
    __shared__ float4 s_pt[TILE];
    __shared__ u64    s_col[4][QW][CAP];
    __shared__ int    s_cnt[4][QW];

    const int t     = threadIdx.x;
    const int wave  = t >> 6;
    const int lane  = t & 63;
    const int qbase = (blockIdx.x * 4 + wave) * QW;

    float m2x[QW], m2y[QW], m2z[QW], qb[QW];
    #pragma unroll
    for (int qi = 0; qi < QW; ++qi) {
        const float4 q = c4[qbase + qi];
        m2x[qi] = -2.0f * q.x;
        m2y[qi] = -2.0f * q.y;
        m2z[qi] = -2.0f * q.z;
        qb[qi]  = q.w;
    }
    if (lane < QW) s_cnt[wave][lane] = 0;

    float bd[QW];
    #pragma unroll
    for (int qi = 0; qi < QW; ++qi) bd[qi] = 3.0e38f;

    for (int l = lane; l < SAMPN; l += 128) {
        const float4 c0 = c4[l];
        const float4 c1 = c4[l + 64];
        #pragma unroll
        for (int qi = 0; qi < QW; ++qi) {
            const float d0 = make_d2(c0, m2x[qi], m2y[qi], m2z[qi], qb[qi]);
            const float d1 = make_d2(c1, m2x[qi], m2y[qi], m2z[qi], qb[qi]);
            bd[qi] = fminf(bd[qi], fminf(d0, d1));
        }
    }

    float tauf[QW];
    #pragma unroll
    for (int qi = 0; qi < QW; ++qi) {
        const float s = bitonicf(bd[qi], lane);
        tauf[qi] = __shfl(s, 15);
    }

    for (int tb = 0; tb < NPTS; tb += TILE) {
        __syncthreads();
        for (int jj = t; jj < TILE; jj += 256) s_pt[jj] = c4[tb + jj];
        __syncthreads();
        for (int l = lane; l < TILE; l += 128) {
            const float4 c0 = s_pt[l];
            const float4 c1 = s_pt[l + 64];
            const int j0 = tb + l, j1 = tb + l + 64;
            #pragma unroll
            for (int qi = 0; qi < QW; ++qi) {
                const float d0 = make_d2(c0, m2x[qi], m2y[qi], m2z[qi], qb[qi]);
                const float d1 = make_d2(c1, m2x[qi], m2y[qi], m2z[qi], qb[qi]);
                if (d0 <= tauf[qi]) {
                    const int pos = atomicAdd(&s_cnt[wave][qi], 1);
                    if (pos < CAP)
                        s_col[wave][qi][pos] = ((u64)__float_as_uint(d0) << 32) | (u64)(unsigned)j0;
                }
                if (d1 <= tauf[qi]) {
                    const int pos = atomicAdd(&s_cnt[wave][qi], 1);
                    if (pos < CAP)
                        s_col[wave][qi][pos] = ((u64)__float_as_uint(d1) << 32) | (u64)(unsigned)j1;
                }
            }
        }
    }

    #pragma unroll 1
    for (int qi = 0; qi < QW; ++qi) {
        const int q = qbase + qi;
        int M = s_cnt[wave][qi];

        if (M > CAP) {
            float fb = 3.0e38f;
            for (int l = lane; l < NPTS; l += 64)
                fb = fminf(fb, make_d2(c4[l], m2x[qi], m2y[qi], m2z[qi], qb[qi]));
            const float s    = bitonicf(fb, lane);
            const float tau2 = __shfl(s, 15);
            if (lane == 0) s_cnt[wave][qi] = 0;
            for (int l = lane; l < NPTS; l += 64) {
                const float d = make_d2(c4[l], m2x[qi], m2y[qi], m2z[qi], qb[qi]);
                if (d <= tau2) {
                    const int pos = atomicAdd(&s_cnt[wave][qi], 1);
                    if (pos < CAP)
                        s_col[wave][qi][pos] = ((u64)__float_as_uint(d) << 32) | (u64)(unsigned)l;
                }
            }
            M = s_cnt[wave][qi];
            if (M > CAP) M = CAP;
        }

        if (M <= 64) {
            u64 v = (lane < M) ? s_col[wave][qi][lane] : ~0ull;
            v = bitonic64(v, lane);
            if (lane < KNN) {
                oidx[q * KNN + lane] = (int)(v & 0xffffffffu);
                od2 [q * KNN + lane] = __uint_as_float((unsigned)(v >> 32));
            }
        } else {
            u64 a = (lane < 64) ? s_col[wave][qi][lane] : ~0ull;
            if (lane >= M) a = ~0ull;
            a = bitonic64(a, lane);
            u64 b = (lane + 64 < M) ? s_col[wave][qi][lane + 64] : ~0ull;
            b = bitonic64(b, lane);
            const u64 bs = __shfl(b, lane & 15);
            u64 mv = (lane < 16) ? a : ((lane < 32) ? bs : ~0ull);
            mv = bitonic64(mv, lane);
            if (lane < KNN) {
                oidx[q * KNN + lane] = (int)(mv & 0xffffffffu);
                od2 [q * KNN + lane] = __uint_as_float((unsigned)(mv >> 32));
            }
        }
    }
}

// ---------------------------------------------------------------------------
// Kernel B: three fp32 GEMMs (unchanged).
// ---------------------------------------------------------------------------
__global__ __launch_bounds__(256) void gemm3_kernel(
    const float* __restrict__ x,
    const float* __restrict__ Wq, const float* __restrict__ bq,
    const float* __restrict__ Wk, const float* __restrict__ bk,
    const float* __restrict__ Wv, const float* __restrict__ bv,
    float* __restrict__ xq, float* __restrict__ xk, float* __restrict__ xv) {
    const int which = blockIdx.z;
    const float* W    = (which == 0) ? Wq : (which == 1) ? Wk : Wv;
    const float* bias = (which == 0) ? bq : (which == 1) ? bk : bv;
    float*       out  = (which == 0) ? xq : (which == 1) ? xk : xv;

    const int row0 = blockIdx.x * 64;
    const int col0 = blockIdx.y * 64;

    __shared__ float As[64][68];
    __shared__ float Bs[64][68];

    const int t  = threadIdx.x;
    const int lr = t >> 4;
    const int lc = t & 15;
    const int or0 = (t >> 4) * 4;
    const int oc0 = (t & 15) * 4;

    float acc[4][4] = {};

    for (int kk = 0; kk < CCH; kk += 64) {
        __syncthreads();
        #pragma unroll
        for (int i = 0; i < 4; ++i) {
            const int r = lr + i * 16;
            *(float4*)&As[r][lc * 4] =
                *(const float4*)&x[(size_t)(row0 + r) * CCH + kk + lc * 4];
            *(float4*)&Bs[r][lc * 4] =
                *(const float4*)&W[(size_t)(kk + r) * CCH + col0 + lc * 4];
        }
        __syncthreads();
        #pragma unroll 8
        for (int k = 0; k < 64; ++k) {
            const float a0 = As[or0 + 0][k];
            const float a1 = As[or0 + 1][k];
            const float a2 = As[or0 + 2][k];
            const float a3 = As[or0 + 3][k];
            const float4 b = *(const float4*)&Bs[k][oc0];
            acc[0][0] += a0 * b.x; acc[0][1] += a0 * b.y; acc[0][2] += a0 * b.z; acc[0][3] += a0 * b.w;
            acc[1][0] += a1 * b.x; acc[1][1] += a1 * b.y; acc[1][2] += a1 * b.z; acc[1][3] += a1 * b.w;
            acc[2][0] += a2 * b.x; acc[2][1] += a2 * b.y; acc[2][2] += a2 * b.z; acc[2][3] += a2 * b.w;
            acc[3][0] += a3 * b.x; acc[3][1] += a3 * b.y; acc[3][2] += a3 * b.z; acc[3][3] += a3 * b.w;
        }
    }

    const float4 bb = *(const float4*)&bias[col0 + oc0];
    #pragma unroll
    for (int i = 0; i < 4; ++i) {
        const int r = row0 + or0 + i;
        float4 o;
        o.x = acc[i][0] + bb.x;
        o.y = acc[i][1] + bb.y;
        o.z = acc[i][2] + bb.z;
        o.w = acc[i][3] + bb.w;
        *(float4*)&out[(size_t)r * CCH + col0 + oc0] = o;
    }
}

// ---------------------------------------------------------------------------
// Kernel C: fused per-point attention, v2.
//  - Once-read weight arrays (Wp2 rows, bp2, g2, be2, xq row, bw1/g3/be3/bw2)
//    come straight from global (L1-resident) — no LDS staging, no conflicts.
//  - w1t staged transposed+split with stride 66: writes and reads both 2-way
//    bank aliased (free).
//  - Single barrier covers staging + phase-1 LDS writes.
// ---------------------------------------------------------------------------
__global__ __launch_bounds__(256) void fused_kernel(
    const float* __restrict__ p,
    const float* __restrict__ xqg, const float* __restrict__ xkg, const float* __restrict__ xvg,
    const int* __restrict__ nidx, const float* __restrict__ nd2,
    const float* __restrict__ Wp1, const float* __restrict__ bp1,
    const float* __restrict__ g1,  const float* __restrict__ be1,
    const float* __restrict__ Wp2, const float* __restrict__ bp2,
    const float* __restrict__ g2,  const float* __restrict__ be2,
    const float* __restrict__ Ww1, const float* __restrict__ bw1,
    const float* __restrict__ g3,  const float* __restrict__ be3,
    const float* __restrict__ Ww2, const float* __restrict__ bw2,
    float* __restrict__ out) {
    const int i = blockIdx.x;
    const int t = threadIdx.x;

    __shared__ float s_val[16][132];
    __shared__ float s_w1tA[16][66];   // A[m][(c>>3)*4 + (c&3)] = Ww1[c*16+m], c&7 < 4
    __shared__ float s_w1tB[16][66];   // B[m][(c>>3)*4 + (c&3)] = Ww1[c*16+m], c&7 >= 4
    __shared__ float s_r[16][17], s_w2[16][17], s_e[16][17], s_wn[16][17];
    __shared__ float s_ww2[256];       // [mm][m] row-major

    const int k  = t >> 4;      // neighbor 0..15
    const int tl = t & 15;
    const int c0 = tl * 8;

    // ---- issue long-latency loads first ----
    const int   jn  = nidx[i * KNN + k];
    const float d2v = nd2[i * KNN + k];
    const float4 a0 = *(const float4*)&xkg[(size_t)jn * CCH + c0];
    const float4 a1 = *(const float4*)&xkg[(size_t)jn * CCH + c0 + 4];
    const float4 b0 = *(const float4*)&xvg[(size_t)jn * CCH + c0];
    const float4 b1 = *(const float4*)&xvg[(size_t)jn * CCH + c0 + 4];

    // ---- stage Ww1 transposed/split/padded (writes 2-way aliased) ----
    #pragma unroll
    for (int j = 0; j < 8; ++j) {
        const int e2   = t + j * 256;       // = csrc*16 + m
        const int m    = e2 & 15;
        const int csrc = e2 >> 4;
        const int col  = ((csrc >> 3) << 2) | (csrc & 3);
        const float v  = Ww1[e2];
        if (csrc & 4) s_w1tB[m][col] = v;
        else          s_w1tA[m][col] = v;
    }
    s_ww2[t] = Ww2[t];

    // ---- phase 1: pr + wv (regs) + val (LDS) ----
    const float dw  = expf(-sqrtf(fmaxf(d2v, 0.f)));
    const float prx = p[jn * 3 + 0] - p[i * 3 + 0];
    const float pry = p[jn * 3 + 1] - p[i * 3 + 1];
    const float prz = p[jn * 3 + 2] - p[i * 3 + 2];
    float tt[3];
    #pragma unroll
    for (int e = 0; e < 3; ++e) {
        float v = prx * Wp1[0 * 3 + e] + pry * Wp1[1 * 3 + e] + prz * Wp1[2 * 3 + e] + bp1[e];
        v = v * (g1[e] * BN_RS) + be1[e];
        tt[e] = fmaxf(v, 0.f);
    }

    float wv8[8];
    #pragma unroll
    for (int h = 0; h < 2; ++h) {
        const int cc = c0 + h * 4;
        const float4 xk4 = h ? a1 : a0;
        const float4 xv4 = h ? b1 : b0;
        const float4 w0  = *(const float4*)&Wp2[cc];
        const float4 w1  = *(const float4*)&Wp2[128 + cc];
        const float4 w2  = *(const float4*)&Wp2[256 + cc];
        const float4 bp  = *(const float4*)&bp2[cc];
        const float4 xq4 = *(const float4*)&xqg[(size_t)i * CCH + cc];
        const float4 gg  = *(const float4*)&g2[cc];
        const float4 bb  = *(const float4*)&be2[cc];
        float4 val4;
        {
            const float pr = tt[0] * w0.x + tt[1] * w1.x + tt[2] * w2.x + bp.x;
            float wvv = (xq4.x - xk4.x) + pr;
            wv8[h * 4 + 0] = fmaxf(wvv * (gg.x * BN_RS) + bb.x, 0.f);
            val4.x = xv4.x * dw + pr;
        }
        {
            const float pr = tt[0] * w0.y + tt[1] * w1.y + tt[2] * w2.y + bp.y;
            float wvv = (xq4.y - xk4.y) + pr;
            wv8[h * 4 + 1] = fmaxf(wvv * (gg.y * BN_RS) + bb.y, 0.f);
            val4.y = xv4.y * dw + pr;
        }
        {
            const float pr = tt[0] * w0.z + tt[1] * w1.z + tt[2] * w2.z + bp.z;
            float wvv = (xq4.z - xk4.z) + pr;
            wv8[h * 4 + 2] = fmaxf(wvv * (gg.z * BN_RS) + bb.z, 0.f);
            val4.z = xv4.z * dw + pr;
        }
        {
            const float pr = tt[0] * w0.w + tt[1] * w1.w + tt[2] * w2.w + bp.w;
            float wvv = (xq4.w - xk4.w) + pr;
            wv8[h * 4 + 3] = fmaxf(wvv * (gg.w * BN_RS) + bb.w, 0.f);
            val4.w = xv4.w * dw + pr;
        }
        *(float4*)&s_val[k][cc] = val4;
    }
    __syncthreads();   // covers w1t/ww2 staging + s_val writes

    // ---- phase 2: all-m partials then butterfly transpose-reduce ----
    float pp[16];
    #pragma unroll
    for (int m = 0; m < 16; ++m) {
        const float4 a = *(const float4*)&s_w1tA[m][tl * 4];
        const float4 b = *(const float4*)&s_w1tB[m][tl * 4];
        pp[m] = wv8[0] * a.x + wv8[1] * a.y + wv8[2] * a.z + wv8[3] * a.w
              + wv8[4] * b.x + wv8[5] * b.y + wv8[6] * b.z + wv8[7] * b.w;
    }
    float q8[8];
    #pragma unroll
    for (int j = 0; j < 8; ++j) {
        const float send = (tl & 8) ? pp[j] : pp[j + 8];
        const float keep = (tl & 8) ? pp[j + 8] : pp[j];
        q8[j] = keep + __shfl_xor(send, 8);
    }
    float q4[4];
    #pragma unroll
    for (int j = 0; j < 4; ++j) {
        const float send = (tl & 4) ? q8[j] : q8[j + 4];
        const float keep = (tl & 4) ? q8[j + 4] : q8[j];
        q4[j] = keep + __shfl_xor(send, 4);
    }
    float q2[2];
    #pragma unroll
    for (int j = 0; j < 2; ++j) {
        const float send = (tl & 2) ? q4[j] : q4[j + 2];
        const float keep = (tl & 2) ? q4[j + 2] : q4[j];
        q2[j] = keep + __shfl_xor(send, 2);
    }
    const float send1 = (tl & 1) ? q2[0] : q2[1];
    const float keep1 = (tl & 1) ? q2[1] : q2[0];
    const float w1sum = keep1 + __shfl_xor(send1, 1);

    const int m = tl;                       // lane (k, m) holds w1[k][m]
    const float accv = w1sum + bw1[m];
    const float rr   = fmaxf(accv * (g3[m] * BN_RS) + be3[m], 0.f);
    s_r[k][m] = rr;
    __syncthreads();

    float acc2 = bw2[m];
    #pragma unroll
    for (int mm = 0; mm < 16; ++mm) acc2 += s_r[k][mm] * s_ww2[mm * 16 + m];
    s_w2[k][m] = acc2;
    __syncthreads();

    // ---- phase 3: softmax over k ----
    float mx = s_w2[0][m];
    #pragma unroll
    for (int kk = 1; kk < 16; ++kk) mx = fmaxf(mx, s_w2[kk][m]);
    const float ev = expf(acc2 - mx);
    s_e[k][m] = ev;
    __syncthreads();
    float ssum = 0.f;
    #pragma unroll
    for (int kk = 0; kk < 16; ++kk) ssum += s_e[kk][m];
    s_wn[k][m] = ev / ssum;
    __syncthreads();

    // ---- phase 4 ----
    if (t < 128) {
        const int c = t, mc = t & 15;
        float o = 0.f;
        #pragma unroll
        for (int kk = 0; kk < 16; ++kk) o += s_val[kk][c] * s_wn[kk][mc];
        out[(size_t)i * CCH + c] = o;
    }
}

// ---------------------------------------------------------------------------
extern "C" void kernel_launch(void* const* d_in, const int* in_sizes, int n_in,
                              void* d_out, int out_size, void* d_ws, size_t ws_size,
                              hipStream_t stream) {
    (void)in_sizes; (void)n_in; (void)out_size; (void)ws_size;
    const float* p   = (const float*)d_in[0];
    const float* x   = (const float*)d_in[1];
    const float* Wq  = (const float*)d_in[2];
    const float* bq  = (const float*)d_in[3];
    const float* Wk  = (const float*)d_in[4];
    const float* bk  = (const float*)d_in[5];
    const float* Wv  = (const float*)d_in[6];
    const float* bv  = (const float*)d_in[7];
    const float* Wp1 = (const float*)d_in[8];
    const float* bp1 = (const float*)d_in[9];
    const float* g1  = (const float*)d_in[10];
    const float* be1 = (const float*)d_in[11];
    const float* Wp2 = (const float*)d_in[12];
    const float* bp2 = (const float*)d_in[13];
    const float* g2  = (const float*)d_in[14];
    const float* be2 = (const float*)d_in[15];
    const float* Ww1 = (const float*)d_in[16];
    const float* bw1 = (const float*)d_in[17];
    const float* g3  = (const float*)d_in[18];
    const float* be3 = (const float*)d_in[19];
    const float* Ww2 = (const float*)d_in[20];
    const float* bw2 = (const float*)d_in[21];
    float* out = (float*)d_out;

    // workspace layout
    char* ws = (char*)d_ws;
    int*    idxb = (int*)ws;                                   // 512 KB
    float*  d2b  = (float*)(ws + (size_t)512 * 1024);          // 512 KB
    float*  xqb  = (float*)(ws + (size_t)1 * 1024 * 1024);     // 4 MB
    float*  xkb  = (float*)(ws + (size_t)5 * 1024 * 1024);     // 4 MB
    float*  xvb  = (float*)(ws + (size_t)9 * 1024 * 1024);     // 4 MB
    float4* c4b  = (float4*)(ws + (size_t)13 * 1024 * 1024);   // 128 KB

    pack_kernel<<<dim3(NPTS / 256), dim3(256), 0, stream>>>(p, c4b);
    knn_kernel<<<dim3(NPTS / (4 * QW)), dim3(256), 0, stream>>>(c4b, idxb, d2b);
    gemm3_kernel<<<dim3(NPTS / 64, CCH / 64, 3), dim3(256), 0, stream>>>(
        x, Wq, bq, Wk, bk, Wv, bv, xqb, xkb, xvb);
    fused_kernel<<<dim3(NPTS), dim3(256), 0, stream>>>(
        p, xqb, xkb, xvb, idxb, d2b,
        Wp1, bp1, g1, be1, Wp2, bp2, g2, be2, Ww1, bw1, g3, be3, Ww2, bw2, out);
}